// Round 10
// baseline (355.481 us; speedup 1.0000x reference)
//
#include <hip/hip_runtime.h>

typedef unsigned short u16;
typedef short bf16x8 __attribute__((ext_vector_type(8)));
typedef float f32x4 __attribute__((ext_vector_type(4)));

#define BB 2
#define TT 1024
#define DD 768
#define HH 12
#define HD 64
#define FFD 3072
#define NE 4
#define NTOK (BB*TT)
// compact MoE row space: sum_e ceil(cnt[e]/128)*128 <= 4096 + 4*127 = 4604
#define CROWS 4608
#define SLABZ 3538944L   // CROWS*DD elements per FF2 partial slab

#define MFMA16(a, b, c) __builtin_amdgcn_mfma_f32_16x16x32_bf16((a), (b), (c), 0, 0, 0)

#define ASYNC16(gsrc, ldst)                                                    \
    __builtin_amdgcn_global_load_lds(                                          \
        (const __attribute__((address_space(1))) void*)(gsrc),                 \
        (__attribute__((address_space(3))) void*)(ldst), 16, 0, 0)

__device__ __forceinline__ float us2f(u16 u) {
    return __uint_as_float(((unsigned int)u) << 16);
}
__device__ __forceinline__ u16 f2us(float f) {
    unsigned int x = __float_as_uint(f);
    x += 0x7fffu + ((x >> 16) & 1u);
    return (u16)(x >> 16);
}

// ---------------------------------------------------------------------------
// Fused conversion: one launch replaces 5 converts + 3 bias memcpys.
// ---------------------------------------------------------------------------
__global__ __launch_bounds__(256) void convert5_kernel(
    const float* __restrict__ src, const float* __restrict__ wq,
    const float* __restrict__ wk, const float* __restrict__ wv,
    const float* __restrict__ wo,
    const float* __restrict__ bq, const float* __restrict__ bk,
    const float* __restrict__ bv,
    u16* __restrict__ src_h, u16* __restrict__ wqkv_h, u16* __restrict__ wo_h,
    float* __restrict__ bqkv)
{
    const int bid = blockIdx.x, tid = threadIdx.x;
    if (bid == 1920) {
        for (int i = tid; i < 3 * DD; i += 256) {
            float v = (i < DD) ? bq[i] : (i < 2 * DD) ? bk[i - DD] : bv[i - 2 * DD];
            bqkv[i] = v;
        }
        return;
    }
    int i = bid * 256 + tid;
    const float* in; u16* out; int off;
    if (i < 196608) { in = src; out = src_h; off = i; }
    else {
        int j = i - 196608; int w = j / 73728; off = j - w * 73728;
        in = (w == 0) ? wq : (w == 1) ? wk : (w == 2) ? wv : wo;
        out = (w < 3) ? wqkv_h + (size_t)w * (DD * DD) : wo_h;
    }
    const float4* p = reinterpret_cast<const float4*>(in) + (size_t)off * 2;
    float4 a = p[0], b = p[1];
    u16 o[8] = {f2us(a.x), f2us(a.y), f2us(a.z), f2us(a.w),
                f2us(b.x), f2us(b.y), f2us(b.z), f2us(b.w)};
    *reinterpret_cast<uint4*>(out + (size_t)off * 8) = *reinterpret_cast<uint4*>(o);
}

// ---------------------------------------------------------------------------
// Transpose + convert (vectorized): per z, src [.,C] fp32 -> dst bf16 with
// dst[c*dstStride + r]. float4 reads, uint2 (4xbf16) packed writes.
// ---------------------------------------------------------------------------
__global__ __launch_bounds__(256) void transpose_convert_kernel(
    const float* __restrict__ src, u16* __restrict__ dst,
    int C, int dstStride, long srcZ, long dstZ)
{
    __shared__ float tile[32][33];
    const float* s = src + (size_t)blockIdx.z * srcZ;
    u16* d = dst + (size_t)blockIdx.z * dstZ;
    const int c0 = blockIdx.x * 32, r0 = blockIdx.y * 32;
    const int tid = threadIdx.x;
    {
        const int r = tid >> 3, cs = (tid & 7) * 4;
        float4 v = *reinterpret_cast<const float4*>(&s[(size_t)(r0 + r) * C + c0 + cs]);
        tile[r][cs] = v.x; tile[r][cs + 1] = v.y;
        tile[r][cs + 2] = v.z; tile[r][cs + 3] = v.w;
    }
    __syncthreads();
    {
        const int c = tid >> 3, rs = (tid & 7) * 4;
        u16 o[4] = {f2us(tile[rs][c]), f2us(tile[rs + 1][c]),
                    f2us(tile[rs + 2][c]), f2us(tile[rs + 3][c])};
        *reinterpret_cast<uint2*>(&d[(size_t)(c0 + c) * dstStride + r0 + rs]) =
            *reinterpret_cast<uint2*>(o);
    }
}

// ---------------------------------------------------------------------------
// Deterministic compact-slot assignment: single block, Hillis-Steele prefix
// scan over 2048 tokens (8 tokens/thread, 2 entries each).
// ---------------------------------------------------------------------------
__global__ __launch_bounds__(256) void scan_build_kernel(
    const int* __restrict__ epack, int* __restrict__ cnt,
    int* __restrict__ rowtok, int* __restrict__ tok2row)
{
    __shared__ int sc[256][4];
    const int tid = threadIdx.x;
    for (int i = tid; i < CROWS; i += 256) rowtok[i] = 0;
    int ep[8];
    int l0 = 0, l1 = 0, l2 = 0, l3 = 0;
    #pragma unroll
    for (int i = 0; i < 8; i++) {
        const int v = epack[tid * 8 + i];
        ep[i] = v;
        const int a = v & 15, b = (v >> 4) & 15;
        l0 += (a == 0) + (b == 0);
        l1 += (a == 1) + (b == 1);
        l2 += (a == 2) + (b == 2);
        l3 += (a == 3) + (b == 3);
    }
    sc[tid][0] = l0; sc[tid][1] = l1; sc[tid][2] = l2; sc[tid][3] = l3;
    __syncthreads();
    for (int off = 1; off < 256; off <<= 1) {
        int v0 = 0, v1 = 0, v2 = 0, v3 = 0;
        if (tid >= off) {
            v0 = sc[tid - off][0]; v1 = sc[tid - off][1];
            v2 = sc[tid - off][2]; v3 = sc[tid - off][3];
        }
        __syncthreads();
        if (tid >= off) {
            sc[tid][0] += v0; sc[tid][1] += v1;
            sc[tid][2] += v2; sc[tid][3] += v3;
        }
        __syncthreads();
    }
    const int t0 = sc[255][0], t1 = sc[255][1], t2 = sc[255][2], t3 = sc[255][3];
    if (tid == 0) { cnt[0] = t0; cnt[1] = t1; cnt[2] = t2; cnt[3] = t3; }
    const int b1 = (t0 + 127) & ~127;
    const int b2 = b1 + ((t1 + 127) & ~127);
    const int b3 = b2 + ((t2 + 127) & ~127);
    int r0 = sc[tid][0] - l0;
    int r1 = b1 + sc[tid][1] - l1;
    int r2 = b2 + sc[tid][2] - l2;
    int r3 = b3 + sc[tid][3] - l3;
    #pragma unroll
    for (int i = 0; i < 8; i++) {
        const int t = tid * 8 + i;
        const int a = ep[i] & 15, b = (ep[i] >> 4) & 15;
        const int ra = (a == 0) ? r0++ : (a == 1) ? r1++ : (a == 2) ? r2++ : r3++;
        rowtok[ra] = t; tok2row[t * 2] = ra;
        const int rb = (b == 0) ? r0++ : (b == 1) ? r1++ : (b == 2) ? r2++ : r3++;
        rowtok[rb] = t; tok2row[t * 2 + 1] = rb;
    }
}

// ---------------------------------------------------------------------------
// bf16 MFMA GEMM: C[M,N] = A[M,K] * Bt[N,K]^T. 128x128 tile, 4 waves, BK=64.
// DB=1: double-buffered LDS (64 KB) with counted-wait prefetch loop (for
// grid-starved QKV/Wo). DB=0: single buffer (FF1/FF2 keep >=3 blocks/CU).
// Staging swizzle: col group (lane&7)^(row&7) on the GLOBAL source side,
// mirrored on fragment reads -> conflict-free b128 (LDS dest stays linear).
// modes: 0 QKV (LDS-repacked Q/K row stores + V transpose-through-LDS),
// 2 FF1 compact, 3 Wo split-K partials, 4 FF2 compact.
// swz: 0 3D grid; 1 FF1 XCD map; 2 QKV XCD-chunked flat; 3 FF2 XCD map.
// ---------------------------------------------------------------------------
template<int DB>
__global__ __launch_bounds__(256) void gemm_bt_kernel(
    const u16* __restrict__ A, int lda, long aZ,
    const u16* __restrict__ Bt, int ldb, long bZ,
    int K, int mode, int swz,
    float* __restrict__ outF, u16* __restrict__ outH,
    u16* __restrict__ outH2, u16* __restrict__ outH3,
    int ldc, long cZ,
    const float* __restrict__ biasF, int biasZ,
    const int* __restrict__ rowtok, const int* __restrict__ cntp,
    const float* __restrict__ comb)
{
    __shared__ __align__(16) u16 As[(DB ? 2 : 1) * 128 * 64];
    __shared__ __align__(16) u16 Bs[(DB ? 2 : 1) * 128 * 64];
    const int tid = threadIdx.x;
    int bx, by, z, e = 0, baseE = 0;
    if (swz == 3) {
        const int fid = blockIdx.x;
        const int xcd = fid & 7; int r = fid >> 3;
        const int half = (r >= 96) ? 1 : 0; r -= half * 96;
        bx = r % 6; by = r / 6;
        const int ez = xcd * 2 + half; e = ez >> 2; z = ez & 3;
    } else if (swz == 1) {
        const int fid = blockIdx.x;
        const int xcd = fid & 7; const int r = fid >> 3;
        const int ne = xcd * 12 + (r % 12);
        by = r / 12; bx = ne % 24; e = ne / 24; z = e;
    } else if (swz == 2) {
        // QKV flat 288: each XCD owns 36 consecutive (bx,by) blocks (by-major)
        const int fid = blockIdx.x;
        const int g = (fid & 7) * 36 + (fid >> 3);
        by = g & 15; bx = g >> 4; z = 0;
    } else {
        bx = blockIdx.x; by = blockIdx.y; z = blockIdx.z;
    }
    if (mode == 2 || mode == 4) {
        const int q0 = (cntp[0] + 127) & ~127;
        const int q1 = (cntp[1] + 127) & ~127;
        const int q2 = (cntp[2] + 127) & ~127;
        baseE = (e > 0 ? q0 : 0) + (e > 1 ? q1 : 0) + (e > 2 ? q2 : 0);
        if (by * 128 >= cntp[e]) return;   // uniform per block: safe early-exit
    }
    const int m0 = by * 128, n0 = bx * 128;
    const u16* Ab = A + (size_t)z * aZ;
    const u16* Bb = Bt + (size_t)z * bZ;
    if (mode == 4) {
        Ab += (size_t)baseE * lda;
        Bb += (size_t)e * ((size_t)DD * FFD);
    }

    const int wave = tid >> 6, lane = tid & 63;
    const int wm = (wave & 1) * 64, wn = (wave >> 1) * 64;
    const int fm = lane & 15;
    const int g  = lane >> 4;

    // staging: wave w covers tile rows [w*32, w*32+32); 4 instrs per operand,
    // instr i covers rows +[i*8, i*8+8). XOR col-group swizzle on global side.
    const int lr8 = lane >> 3;
    const int cg  = ((lane & 7) ^ lr8) * 8;   // swizzled global col (u16)
    const u16 *aG[4], *bG[4];
    u16 *aL[4], *bL[4];
    #pragma unroll
    for (int i = 0; i < 4; i++) {
        const int rr = wave * 32 + i * 8 + lr8;
        int arow;
        if (mode == 2) arow = rowtok[baseE + m0 + rr];
        else           arow = m0 + rr;
        aG[i] = Ab + (size_t)arow * lda + cg;
        bG[i] = Bb + (size_t)(n0 + rr) * ldb + cg;
        aL[i] = &As[(wave * 32 + i * 8) * 64];
        bL[i] = &Bs[(wave * 32 + i * 8) * 64];
    }

#define STAGE(B, KO) do {                                                      \
        const int _o = (B) * (128 * 64);                                       \
        _Pragma("unroll")                                                      \
        for (int _i = 0; _i < 4; _i++) ASYNC16(aG[_i] + (KO), aL[_i] + _o);    \
        _Pragma("unroll")                                                      \
        for (int _i = 0; _i < 4; _i++) ASYNC16(bG[_i] + (KO), bL[_i] + _o);    \
    } while (0)

    // fragment reads: global col g*8 + ks*32 lives at LDS group
    // ((g + ks*4) ^ (row&7)); row&7 == fm&7 for rows wm+i*16+fm
    const int c0 = ((g    ) ^ (fm & 7)) * 8;
    const int c1 = ((g + 4) ^ (fm & 7)) * 8;
    const u16* pa[4]; const u16* pb[4];
    #pragma unroll
    for (int i = 0; i < 4; i++) {
        pa[i] = &As[(wm + i * 16 + fm) * 64];
        pb[i] = &Bs[(wn + i * 16 + fm) * 64];
    }

    f32x4 acc[4][4] = {};
    int buf = 0;
    if (DB) STAGE(0, 0);

    for (int k0 = 0; k0 < K; k0 += 64) {
        if (DB) {
            asm volatile("s_waitcnt vmcnt(0)" ::: "memory");
            __builtin_amdgcn_s_barrier();
            __builtin_amdgcn_sched_barrier(0);
            if (k0 + 64 < K) STAGE(buf ^ 1, k0 + 64);
        } else {
            STAGE(0, k0);
            __syncthreads();
        }
        const int bo = DB ? buf * (128 * 64) : 0;
        #pragma unroll
        for (int ks = 0; ks < 2; ks++) {
            const int cc = bo + (ks ? c1 : c0);
            bf16x8 af[4], bf[4];
            #pragma unroll
            for (int i = 0; i < 4; i++)
                af[i] = *reinterpret_cast<const bf16x8*>(pa[i] + cc);
            #pragma unroll
            for (int j = 0; j < 4; j++)
                bf[j] = *reinterpret_cast<const bf16x8*>(pb[j] + cc);
            #pragma unroll
            for (int i = 0; i < 4; i++)
                #pragma unroll
                for (int j = 0; j < 4; j++)
                    acc[i][j] = MFMA16(af[i], bf[j], acc[i][j]);
        }
        if (DB) buf ^= 1;
        else    __syncthreads();
    }
    if (DB) __syncthreads();
#undef STAGE

    // C/D layout: col = lane&15, row = (lane>>4)*4 + reg   [m89-verified]
    const int cn = lane & 15, cr = (lane >> 4) * 4;

    if (mode == 0) {
        // LDS-repacked epilogue, 4 passes x 32 rows.
        const int which = (n0 >= 1536) ? 2 : (n0 >= 768 ? 1 : 0);
        const int nb = n0 - which * 768;
        u16* outP = (which == 0) ? outH : (which == 1) ? outH2 : outH3;
        u16* Cs = As;
        #pragma unroll
        for (int i = 0; i < 4; i++) {
            if (i) __syncthreads();
            #pragma unroll
            for (int j = 0; j < 4; j++) {
                const int n = n0 + wn + j * 16 + cn;
                const float bias = biasF[n];
                #pragma unroll
                for (int r = 0; r < 4; r++) {
                    Cs[((wave & 1) * 16 + cr + r) * 128 + wn + j * 16 + cn] =
                        f2us(acc[i][j][r] + bias);
                }
            }
            __syncthreads();
            if (which < 2) {
                // Q/K: row stores, 16 u16 per thread within one head's 64-run
                const int lr2 = tid >> 3, c2 = (tid & 7) * 16;
                const int m2 = m0 + (lr2 >> 4) * 64 + i * 16 + (lr2 & 15);
                const int bb2 = m2 >> 10, t2 = m2 & 1023;
                const int hh = (nb + c2) >> 6, d0 = (nb + c2) & 63;
                u16* dst = outP + (((size_t)(bb2 * HH + hh) * TT + t2) << 6) + d0;
                *reinterpret_cast<uint4*>(dst) =
                    *reinterpret_cast<const uint4*>(&Cs[lr2 * 128 + c2]);
                *reinterpret_cast<uint4*>(dst + 8) =
                    *reinterpret_cast<const uint4*>(&Cs[lr2 * 128 + c2 + 8]);
            } else {
                // V: transpose through LDS; 16B stores along t.
                const int nl = tid >> 1, half = tid & 1;
                const int hh = (nb + nl) >> 6, d = (nb + nl) & 63;
                #pragma unroll
                for (int seg = 0; seg < 2; seg++) {
                    u16 o[8];
                    #pragma unroll
                    for (int k = 0; k < 8; k++)
                        o[k] = Cs[(seg * 16 + half * 8 + k) * 128 + nl];
                    const int t0 = m0 + seg * 64 + i * 16 + half * 8;
                    const int bb2 = t0 >> 10, tt2 = t0 & 1023;
                    u16* dst = outP + (((size_t)(bb2 * HH + hh) * HD + d) << 10) + tt2;
                    *reinterpret_cast<uint4*>(dst) = *reinterpret_cast<uint4*>(o);
                }
            }
        }
        return;
    }

    if (mode == 2) {
        // LDS-repacked epilogue: 4 passes x 32 rows, dwordx4 coalesced stores
        u16* Cs = As;
        #pragma unroll
        for (int i = 0; i < 4; i++) {
            if (i) __syncthreads();
            int tokr[4]; float combr[4];
            #pragma unroll
            for (int r = 0; r < 4; r++)
                tokr[r] = rowtok[baseE + m0 + wm + i * 16 + cr + r];
            #pragma unroll
            for (int r = 0; r < 4; r++)
                combr[r] = comb[(size_t)tokr[r] * NE + z];
            #pragma unroll
            for (int j = 0; j < 4; j++) {
                const int n = n0 + wn + j * 16 + cn;
                const float bias = biasF[(size_t)z * biasZ + n];
                #pragma unroll
                for (int r = 0; r < 4; r++) {
                    float y = fmaxf(acc[i][j][r] + bias, 0.f) * combr[r];
                    Cs[((wave & 1) * 16 + cr + r) * 128 + wn + j * 16 + cn] = f2us(y);
                }
            }
            __syncthreads();
            const int lr2 = tid >> 3, c2 = (tid & 7) * 16;
            const int m2 = m0 + (lr2 >> 4) * 64 + i * 16 + (lr2 & 15);
            u16* dst = outH + (size_t)(baseE + m2) * ldc + n0 + c2;
            *reinterpret_cast<uint4*>(dst) =
                *reinterpret_cast<const uint4*>(&Cs[lr2 * 128 + c2]);
            *reinterpret_cast<uint4*>(dst + 8) =
                *reinterpret_cast<const uint4*>(&Cs[lr2 * 128 + c2 + 8]);
        }
        return;
    }

    #pragma unroll
    for (int i = 0; i < 4; i++) {
        #pragma unroll
        for (int j = 0; j < 4; j++) {
            const int n = n0 + wn + j * 16 + cn;
            #pragma unroll
            for (int r = 0; r < 4; r++) {
                const int m = m0 + wm + i * 16 + cr + r;
                // mode 3 (baseE=0) and mode 4 (compact rows)
                float* basep = outF + (size_t)z * cZ;
                basep[(size_t)(baseE + m) * ldc + n] = acc[i][j][r];
            }
        }
    }
}

// ---------------------------------------------------------------------------
// MFMA attention. Block = (qt 16 rows, head). 4 waves, QBLK=16.
// R10: body identical to R9; ONLY change is an XCD-affine grid decode.
// Old 2D grid (qt fast) round-robined each head's 64 blocks across all 8
// XCDs -> K/V (256 KB/head) replicated in every XCD L2, FETCH 26 MB (~3x
// ideal), HBM-miss latency (~900cy) on the serialized load rounds.
// New flat 1536 map: xcd=fid&7; r=fid>>3; bh=xcd*3+r/64; qt=r%64 ->
// each XCD owns 3 whole heads (768 KB K/V, L2-resident).
// ---------------------------------------------------------------------------
#define PSTR 1032  // u16 stride: byte stride 2064 (16B aligned), dw 516 ≡ 4 mod 8 -> conflict-free b128
__global__ __launch_bounds__(256, 3) void attn_mfma_kernel(
    const u16* __restrict__ Qh, const u16* __restrict__ Kh,
    const u16* __restrict__ VT, const float* __restrict__ gamma_p,
    u16* __restrict__ attn_out)
{
    __shared__ __align__(16) u16 P[16 * PSTR];
    __shared__ __align__(16) float wred[4][16][4];
    __shared__ __align__(16) float dred[16][4];

    const int fid = blockIdx.x;
    const int xcd = fid & 7, rr = fid >> 3;
    const int bh = xcd * 3 + (rr >> 6);     // 24 heads: 3 per XCD
    const int qt = rr & 63;
    const int b = bh / HH, h = bh - b * HH;
    const int tid = threadIdx.x, wave = tid >> 6, lane = tid & 63;
    const int g = lane >> 4, fm = lane & 15;
    const float gamma = gamma_p[0];
    const int m0 = qt * 16;
    const u16* Qp = Qh + (size_t)bh * TT * HD;
    const u16* Kp = Kh + (size_t)bh * TT * HD;
    const u16* Vp = VT + (size_t)bh * HD * TT;

    bf16x8 af[2];
    #pragma unroll
    for (int ks = 0; ks < 2; ks++)
        af[ks] = *reinterpret_cast<const bf16x8*>(
            Qp + (size_t)(m0 + fm) * HD + ks * 32 + g * 8);

    const int n0w = wave * 256;
    f32x4 acc[16] = {};
    #pragma unroll
    for (int nj = 0; nj < 16; nj++) {
        const u16* kp = Kp + (size_t)(n0w + nj * 16 + fm) * HD + g * 8;
        bf16x8 b0 = *reinterpret_cast<const bf16x8*>(kp);
        bf16x8 b1 = *reinterpret_cast<const bf16x8*>(kp + 32);
        acc[nj] = MFMA16(af[0], b0, acc[nj]);
        acc[nj] = MFMA16(af[1], b1, acc[nj]);
    }

    // ---- per-wave row stats -> LDS ----
    #pragma unroll
    for (int r = 0; r < 4; r++) {
        float s1 = 0.f, s2 = 0.f, mx = -3.4e38f, mn = 3.4e38f;
        #pragma unroll
        for (int nj = 0; nj < 16; nj++) {
            float v = acc[nj][r];
            s1 += v; s2 = fmaf(v, v, s2);
            mx = fmaxf(mx, v); mn = fminf(mn, v);
        }
        #pragma unroll
        for (int msk = 1; msk < 16; msk <<= 1) {
            s1 += __shfl_xor(s1, msk);
            s2 += __shfl_xor(s2, msk);
            mx = fmaxf(mx, __shfl_xor(mx, msk));
            mn = fminf(mn, __shfl_xor(mn, msk));
        }
        if (fm == 0) {
            const int row = g * 4 + r;
            wred[wave][row][0] = s1; wred[wave][row][1] = s2;
            wred[wave][row][2] = mx; wred[wave][row][3] = mn;
        }
    }
    __syncthreads();   // barrier 1: wred complete

    // ---- inline combine + softmax (a/cm are loop-local temps) ----
    #pragma unroll
    for (int r = 0; r < 4; r++) {
        const int row = g * 4 + r;
        float s1 = 0.f, s2 = 0.f, mx = -3.4e38f, mn = 3.4e38f;
        #pragma unroll
        for (int w = 0; w < 4; w++) {
            float4 t = *reinterpret_cast<const float4*>(&wred[w][row][0]);
            s1 += t.x; s2 += t.y;
            mx = fmaxf(mx, t.z); mn = fminf(mn, t.w);
        }
        float var = (s2 - s1 * s1 * (1.f / TT)) * (1.f / (TT - 1));
        var = fmaxf(var, 0.f);
        const float a = gamma / (sqrtf(var) + 8e-5f);
        const float cm = (a >= 0.f) ? a * mx : a * mn;
        float dp = 0.f;
        #pragma unroll
        for (int nj = 0; nj < 16; nj++) {
            float p = __expf(fmaf(a, acc[nj][r], -cm));
            u16 pb = f2us(p);
            dp += us2f(pb);
            P[row * PSTR + n0w + nj * 16 + fm] = pb;
        }
        #pragma unroll
        for (int msk = 1; msk < 16; msk <<= 1) dp += __shfl_xor(dp, msk);
        if (fm == 0) dred[row][wave] = dp;
    }
    __syncthreads();   // barrier 2: P + dred complete

    // ---- PV (direct loads; unroll 8 -> deeper load window) ----
    f32x4 oacc = {};
    #pragma unroll 8
    for (int ks = 0; ks < 32; ks++) {
        bf16x8 bv = *reinterpret_cast<const bf16x8*>(
            Vp + (size_t)(wave * 16 + fm) * TT + ks * 32 + g * 8);
        bf16x8 a0 = *reinterpret_cast<const bf16x8*>(&P[(size_t)fm * PSTR + ks * 32 + g * 8]);
        oacc = MFMA16(a0, bv, oacc);
    }

    // ---- epilogue: dinv folded here ----
    #pragma unroll
    for (int r = 0; r < 4; r++) {
        const int row = g * 4 + r;
        float4 dv = *reinterpret_cast<const float4*>(&dred[row][0]);
        const float dinv = 1.f / (dv.x + dv.y + dv.z + dv.w);
        const int t = m0 + row;
        attn_out[((size_t)(b * TT + t)) * DD + h * HD + wave * 16 + fm] =
            f2us(oacc[r] * dinv);
    }
}

// ---------------------------------------------------------------------------
// LN1 fused + gate: layernorm -> x fp32 + xh bf16; gate on in-register
// post-LN values; thread-0 softmax/top-2 -> comb, epack.
// ---------------------------------------------------------------------------
__global__ __launch_bounds__(256) void ln1_kernel(
    const float* __restrict__ p0, const float* __restrict__ p1,
    const float* __restrict__ p2, const float* __restrict__ p3,
    const float* __restrict__ src, const float* __restrict__ bo,
    const float* __restrict__ g, const float* __restrict__ bta,
    const float* __restrict__ Wg, const float* __restrict__ bg,
    float* __restrict__ outF, u16* __restrict__ outH,
    float* __restrict__ comb, int* __restrict__ epack)
{
    const int row = blockIdx.x, tid = threadIdx.x;
    __shared__ float red[256];
    __shared__ float gred[4][4];
    const size_t base = (size_t)row * DD;
    float v[3];
    #pragma unroll
    for (int i = 0; i < 3; i++) {
        int c = tid + i * 256;
        v[i] = p0[base + c] + p1[base + c] + p2[base + c] + p3[base + c]
             + src[base + c] + bo[c];
    }
    float s = v[0] + v[1] + v[2];
    red[tid] = s; __syncthreads();
    #pragma unroll
    for (int o = 128; o > 0; o >>= 1) { if (tid < o) red[tid] += red[tid + o]; __syncthreads(); }
    const float mean = red[0] * (1.f / 768.f);
    __syncthreads();
    float qv = 0.f;
    #pragma unroll
    for (int i = 0; i < 3; i++) { float d = v[i] - mean; qv += d * d; }
    red[tid] = qv; __syncthreads();
    #pragma unroll
    for (int o = 128; o > 0; o >>= 1) { if (tid < o) red[tid] += red[tid + o]; __syncthreads(); }
    const float var = red[0] * (1.f / 768.f);
    const float rs = rsqrtf(var + 1e-5f);
    float ga0 = 0.f, ga1 = 0.f, ga2 = 0.f, ga3 = 0.f;
    #pragma unroll
    for (int i = 0; i < 3; i++) {
        int c = tid + i * 256;
        float o = (v[i] - mean) * rs * g[c] + bta[c];
        outF[base + c] = o;
        outH[base + c] = f2us(o);
        ga0 = fmaf(o, Wg[c], ga0);
        ga1 = fmaf(o, Wg[DD + c], ga1);
        ga2 = fmaf(o, Wg[2 * DD + c], ga2);
        ga3 = fmaf(o, Wg[3 * DD + c], ga3);
    }
    #pragma unroll
    for (int off = 32; off > 0; off >>= 1) {
        ga0 += __shfl_down(ga0, off, 64);
        ga1 += __shfl_down(ga1, off, 64);
        ga2 += __shfl_down(ga2, off, 64);
        ga3 += __shfl_down(ga3, off, 64);
    }
    const int wave = tid >> 6, lane = tid & 63;
    if (lane == 0) {
        gred[wave][0] = ga0; gred[wave][1] = ga1;
        gred[wave][2] = ga2; gred[wave][3] = ga3;
    }
    __syncthreads();
    if (tid == 0) {
        float gg[NE];
        #pragma unroll
        for (int e = 0; e < NE; e++)
            gg[e] = gred[0][e] + gred[1][e] + gred[2][e] + gred[3][e] + bg[e];
        float m = -1e30f;
        #pragma unroll
        for (int e = 0; e < NE; e++) m = fmaxf(m, gg[e]);
        float ex[NE], ssum = 0.f;
        #pragma unroll
        for (int e = 0; e < NE; e++) { ex[e] = __expf(gg[e] - m); ssum += ex[e]; }
        #pragma unroll
        for (int e = 0; e < NE; e++) ex[e] /= ssum;
        int e1 = 0;
        #pragma unroll
        for (int e = 1; e < NE; e++) if (ex[e] > ex[e1]) e1 = e;
        int e2 = -1;
        #pragma unroll
        for (int e = 0; e < NE; e++) if (e != e1 && (e2 < 0 || ex[e] > ex[e2])) e2 = e;
        float c[NE] = {0.f, 0.f, 0.f, 0.f};
        c[e1] = ex[e1]; c[e2] = ex[e2];
        #pragma unroll
        for (int e = 0; e < NE; e++) comb[(size_t)row * NE + e] = c[e];
        epack[row] = e1 | (e2 << 4);
    }
}

// ---------------------------------------------------------------------------
// LN2 (compact): t = x + sum_z sum_{i=0,1} pslab[z][tok2row[t,i]] + comb*b2;
// layernorm -> out.
// ---------------------------------------------------------------------------
__global__ __launch_bounds__(256) void ln2_kernel(
    const float* __restrict__ x, const float* __restrict__ pslab,
    const int* __restrict__ tok2row,
    const float* __restrict__ comb, const float* __restrict__ b2,
    const float* __restrict__ g, const float* __restrict__ bta,
    float* __restrict__ outF)
{
    const int row = blockIdx.x, tid = threadIdx.x;
    __shared__ float red[256];
    const size_t base = (size_t)row * DD;
    const int r0 = tok2row[row * 2], r1 = tok2row[row * 2 + 1];
    const float* q0 = pslab + (size_t)r0 * DD;
    const float* q1 = pslab + (size_t)r1 * DD;
    const float c0 = comb[row * NE + 0], c1 = comb[row * NE + 1];
    const float c2 = comb[row * NE + 2], c3 = comb[row * NE + 3];
    float v[3];
    #pragma unroll
    for (int i = 0; i < 3; i++) {
        int c = tid + i * 256;
        float t = x[base + c];
        t += q0[c] + q0[SLABZ + c] + q0[2 * SLABZ + c] + q0[3 * SLABZ + c];
        t += q1[c] + q1[SLABZ + c] + q1[2 * SLABZ + c] + q1[3 * SLABZ + c];
        t = fmaf(c0, b2[c], t);
        t = fmaf(c1, b2[DD + c], t);
        t = fmaf(c2, b2[2 * DD + c], t);
        t = fmaf(c3, b2[3 * DD + c], t);
        v[i] = t;
    }
    float s = v[0] + v[1] + v[2];
    red[tid] = s; __syncthreads();
    #pragma unroll
    for (int o = 128; o > 0; o >>= 1) { if (tid < o) red[tid] += red[tid + o]; __syncthreads(); }
    const float mean = red[0] * (1.f / 768.f);
    __syncthreads();
    float qv = 0.f;
    #pragma unroll
    for (int i = 0; i < 3; i++) { float d = v[i] - mean; qv += d * d; }
    red[tid] = qv; __syncthreads();
    #pragma unroll
    for (int o = 128; o > 0; o >>= 1) { if (tid < o) red[tid] += red[tid + o]; __syncthreads(); }
    const float var = red[0] * (1.f / 768.f);
    const float rs = rsqrtf(var + 1e-5f);
    #pragma unroll
    for (int i = 0; i < 3; i++) {
        int c = tid + i * 256;
        outF[base + c] = (v[i] - mean) * rs * g[c] + bta[c];
    }
}

extern "C" void kernel_launch(void* const* d_in, const int* in_sizes, int n_in,
                              void* d_out, int out_size, void* d_ws, size_t ws_size,
                              hipStream_t stream)
{
    const float* src  = (const float*)d_in[0];
    const float* Wq   = (const float*)d_in[2];  const float* bq = (const float*)d_in[3];
    const float* Wk   = (const float*)d_in[4];  const float* bk = (const float*)d_in[5];
    const float* Wv   = (const float*)d_in[6];  const float* bv = (const float*)d_in[7];
    const float* Wo   = (const float*)d_in[8];  const float* bo = (const float*)d_in[9];
    const float* gam  = (const float*)d_in[10];
    const float* ln1g = (const float*)d_in[11]; const float* ln1b = (const float*)d_in[12];
    const float* ln2g = (const float*)d_in[13]; const float* ln2b = (const float*)d_in[14];
    const float* Wg   = (const float*)d_in[15]; const float* bg = (const float*)d_in[16];
    const float* W1   = (const float*)d_in[17]; const float* b1 = (const float*)d_in[18];
    const float* W2   = (const float*)d_in[19]; const float* b2 = (const float*)d_in[20];
    (void)ws_size; (void)in_sizes; (void)n_in; (void)out_size;

    char* ws = (char*)d_ws;
    u16*   W1T  = (u16*)(ws);
    float* wop  = (float*)(ws + 18874368);
    float* pslab= (float*)(ws);
    u16*   W2T  = (u16*)(ws + 56623104);               // 18,874,368 (live through FF2)
    u16*   hb   = (u16*)(ws + 75497472);               // 28,311,552 compact FF1 out [CROWS][3072]
    float* x    = (float*)(ws + 103809024);            //  6,291,456
    u16*   xh   = (u16*)(ws + 110100480);              //  3,145,728
    float* comb = (float*)(ws + 113246208);            //     32,768
    float* bqkv = (float*)(ws + 113278976);            //      9,216
    int*   cnt    = (int*)(ws + 113288192);            //         64
    int*   rowtok = (int*)(ws + 113288256);            //     18,432 (CROWS)
    int*   epack  = (int*)(ws + 113306688);            //      8,192
    int*   tok2row= (int*)(ws + 113323072);            //     16,384
    // attn-phase aliases inside hb region (all dead before FF1 writes hb)
    char* H = ws + 75497472;
    u16*   Qh     = (u16*)(H);
    u16*   Kh     = (u16*)(H + 3145728);
    u16*   VTh    = (u16*)(H + 6291456);
    u16*   src_h  = (u16*)(H + 9437184);
    u16*   attn_h = (u16*)(H + 12582912);
    u16*   WqkvH  = (u16*)(H + 15728640);
    u16*   WoH    = (u16*)(H + 19267584);
    const long PZ = (long)NTOK * DD;

    // ---- fused conversions (1 launch: src + 4 weights + 3 biases) ----
    convert5_kernel<<<1921, 256, 0, stream>>>(
        src, Wq, Wk, Wv, Wo, bq, bk, bv, src_h, WqkvH, WoH, bqkv);
    transpose_convert_kernel<<<dim3(FFD / 32, DD / 32, NE), 256, 0, stream>>>(
        W1, W1T, FFD, DD, (long)DD * FFD, (long)FFD * DD);
    transpose_convert_kernel<<<dim3(DD / 32, FFD / 32, NE), 256, 0, stream>>>(
        W2, W2T, DD, FFD, (long)FFD * DD, (long)FFD * DD);

    // ---- QKV (dbuf prefetch, XCD-chunked flat 288) ----
    gemm_bt_kernel<1><<<dim3(288, 1, 1), 256, 0, stream>>>(
        src_h, DD, 0, WqkvH, DD, 0, DD, 0, 2,
        nullptr, Qh, Kh, VTh, 0, 0, bqkv, 0, nullptr, nullptr, nullptr);

    // ---- attention (MFMA, XCD-affine head map: each XCD owns 3 heads) ----
    attn_mfma_kernel<<<dim3(1536, 1, 1), 256, 0, stream>>>(
        Qh, Kh, VTh, gam, attn_h);

    // ---- Wo projection split-K x4 (dbuf prefetch) -> fp32 partials ----
    gemm_bt_kernel<1><<<dim3(DD / 128, NTOK / 128, 4), 256, 0, stream>>>(
        attn_h, DD, 192L, WoH, DD, 192L, 192, 3, 0,
        wop, nullptr, nullptr, nullptr, DD, PZ, nullptr, 0, nullptr, nullptr, nullptr);

    // ---- LN1 + fused gate (no atomics) ----
    ln1_kernel<<<NTOK, 256, 0, stream>>>(
        wop, wop + PZ, wop + 2 * PZ, wop + 3 * PZ, src, bo,
        ln1g, ln1b, Wg, bg, x, xh, comb, epack);

    // ---- deterministic slot assignment (single-block prefix scan) ----
    scan_build_kernel<<<1, 256, 0, stream>>>(epack, cnt, rowtok, tok2row);

    // ---- FF1 compact (top-2 only), single-buffer (occupancy) ----
    gemm_bt_kernel<0><<<dim3(1536, 1, 1), 256, 0, stream>>>(
        xh, DD, 0, W1T, DD, (long)FFD * DD, DD, 2, 1,
        nullptr, hb, nullptr, nullptr, FFD, 0, b1, FFD, rowtok, cnt, comb);

    // ---- FF2 compact: per-expert K=3072 split-K x4, single-buffer ----
    gemm_bt_kernel<0><<<dim3(1536, 1, 1), 256, 0, stream>>>(
        hb, FFD, 768L, W2T, FFD, 768L, 768, 4, 3,
        pslab, nullptr, nullptr, nullptr, DD, SLABZ, nullptr, 0, rowtok, cnt, nullptr);

    // ---- LN2 (x + gathered compact partials + comb*b2, then layernorm) ----
    ln2_kernel<<<NTOK, 256, 0, stream>>>(
        x, pslab, tok2row, comb, b2, ln2g, ln2b, (float*)d_out);
}

// Round 11
// 340.802 us; speedup vs baseline: 1.0431x; 1.0431x over previous
//
#include <hip/hip_runtime.h>

typedef unsigned short u16;
typedef short bf16x8 __attribute__((ext_vector_type(8)));
typedef float f32x4 __attribute__((ext_vector_type(4)));

#define BB 2
#define TT 1024
#define DD 768
#define HH 12
#define HD 64
#define FFD 3072
#define NE 4
#define NTOK (BB*TT)
// compact MoE row space: sum_e ceil(cnt[e]/128)*128 <= 4096 + 4*127 = 4604
#define CROWS 4608
#define SLABZ 3538944L   // CROWS*DD elements per FF2 partial slab

#define MFMA16(a, b, c) __builtin_amdgcn_mfma_f32_16x16x32_bf16((a), (b), (c), 0, 0, 0)

#define ASYNC16(gsrc, ldst)                                                    \
    __builtin_amdgcn_global_load_lds(                                          \
        (const __attribute__((address_space(1))) void*)(gsrc),                 \
        (__attribute__((address_space(3))) void*)(ldst), 16, 0, 0)

__device__ __forceinline__ float us2f(u16 u) {
    return __uint_as_float(((unsigned int)u) << 16);
}
__device__ __forceinline__ u16 f2us(float f) {
    unsigned int x = __float_as_uint(f);
    x += 0x7fffu + ((x >> 16) & 1u);
    return (u16)(x >> 16);
}

// ---------------------------------------------------------------------------
// Fused conversion: one launch replaces 5 converts + 3 bias memcpys.
// ---------------------------------------------------------------------------
__global__ __launch_bounds__(256) void convert5_kernel(
    const float* __restrict__ src, const float* __restrict__ wq,
    const float* __restrict__ wk, const float* __restrict__ wv,
    const float* __restrict__ wo,
    const float* __restrict__ bq, const float* __restrict__ bk,
    const float* __restrict__ bv,
    u16* __restrict__ src_h, u16* __restrict__ wqkv_h, u16* __restrict__ wo_h,
    float* __restrict__ bqkv)
{
    const int bid = blockIdx.x, tid = threadIdx.x;
    if (bid == 1920) {
        for (int i = tid; i < 3 * DD; i += 256) {
            float v = (i < DD) ? bq[i] : (i < 2 * DD) ? bk[i - DD] : bv[i - 2 * DD];
            bqkv[i] = v;
        }
        return;
    }
    int i = bid * 256 + tid;
    const float* in; u16* out; int off;
    if (i < 196608) { in = src; out = src_h; off = i; }
    else {
        int j = i - 196608; int w = j / 73728; off = j - w * 73728;
        in = (w == 0) ? wq : (w == 1) ? wk : (w == 2) ? wv : wo;
        out = (w < 3) ? wqkv_h + (size_t)w * (DD * DD) : wo_h;
    }
    const float4* p = reinterpret_cast<const float4*>(in) + (size_t)off * 2;
    float4 a = p[0], b = p[1];
    u16 o[8] = {f2us(a.x), f2us(a.y), f2us(a.z), f2us(a.w),
                f2us(b.x), f2us(b.y), f2us(b.z), f2us(b.w)};
    *reinterpret_cast<uint4*>(out + (size_t)off * 8) = *reinterpret_cast<uint4*>(o);
}

// ---------------------------------------------------------------------------
// Fused W1+W2 transpose+convert, flat grid 18432 (one launch instead of two).
// bid < 9216: W1[e][768][3072] -> W1T[e][3072][768]  (tile grid 96x24 per e)
// else:       W2[e][3072][768] -> W2T[e][768][3072]  (tile grid 24x96 per e)
// ---------------------------------------------------------------------------
__global__ __launch_bounds__(256) void transpose_all_kernel(
    const float* __restrict__ W1, const float* __restrict__ W2,
    u16* __restrict__ W1T, u16* __restrict__ W2T)
{
    __shared__ float tile[32][33];
    const int bid = blockIdx.x, tid = threadIdx.x;
    const float* s; u16* d; int C, dstStride, c0, r0;
    if (bid < 9216) {
        const int e = bid / 2304, rem = bid % 2304;
        c0 = (rem % 96) * 32; r0 = (rem / 96) * 32;
        C = FFD; dstStride = DD;
        s = W1 + (size_t)e * DD * FFD; d = W1T + (size_t)e * FFD * DD;
    } else {
        const int b2 = bid - 9216;
        const int e = b2 / 2304, rem = b2 % 2304;
        c0 = (rem % 24) * 32; r0 = (rem / 24) * 32;
        C = DD; dstStride = FFD;
        s = W2 + (size_t)e * FFD * DD; d = W2T + (size_t)e * FFD * DD;
    }
    {
        const int r = tid >> 3, cs = (tid & 7) * 4;
        float4 v = *reinterpret_cast<const float4*>(&s[(size_t)(r0 + r) * C + c0 + cs]);
        tile[r][cs] = v.x; tile[r][cs + 1] = v.y;
        tile[r][cs + 2] = v.z; tile[r][cs + 3] = v.w;
    }
    __syncthreads();
    {
        const int c = tid >> 3, rs = (tid & 7) * 4;
        u16 o[4] = {f2us(tile[rs][c]), f2us(tile[rs + 1][c]),
                    f2us(tile[rs + 2][c]), f2us(tile[rs + 3][c])};
        *reinterpret_cast<uint2*>(&d[(size_t)(c0 + c) * dstStride + r0 + rs]) =
            *reinterpret_cast<uint2*>(o);
    }
}

// ---------------------------------------------------------------------------
// Deterministic compact-slot assignment: single block, Hillis-Steele prefix
// scan over 2048 tokens (8 tokens/thread, 2 entries each).
// ---------------------------------------------------------------------------
__global__ __launch_bounds__(256) void scan_build_kernel(
    const int* __restrict__ epack, int* __restrict__ cnt,
    int* __restrict__ rowtok, int* __restrict__ tok2row)
{
    __shared__ int sc[256][4];
    const int tid = threadIdx.x;
    for (int i = tid; i < CROWS; i += 256) rowtok[i] = 0;
    int ep[8];
    int l0 = 0, l1 = 0, l2 = 0, l3 = 0;
    #pragma unroll
    for (int i = 0; i < 8; i++) {
        const int v = epack[tid * 8 + i];
        ep[i] = v;
        const int a = v & 15, b = (v >> 4) & 15;
        l0 += (a == 0) + (b == 0);
        l1 += (a == 1) + (b == 1);
        l2 += (a == 2) + (b == 2);
        l3 += (a == 3) + (b == 3);
    }
    sc[tid][0] = l0; sc[tid][1] = l1; sc[tid][2] = l2; sc[tid][3] = l3;
    __syncthreads();
    for (int off = 1; off < 256; off <<= 1) {
        int v0 = 0, v1 = 0, v2 = 0, v3 = 0;
        if (tid >= off) {
            v0 = sc[tid - off][0]; v1 = sc[tid - off][1];
            v2 = sc[tid - off][2]; v3 = sc[tid - off][3];
        }
        __syncthreads();
        if (tid >= off) {
            sc[tid][0] += v0; sc[tid][1] += v1;
            sc[tid][2] += v2; sc[tid][3] += v3;
        }
        __syncthreads();
    }
    const int t0 = sc[255][0], t1 = sc[255][1], t2 = sc[255][2], t3 = sc[255][3];
    if (tid == 0) { cnt[0] = t0; cnt[1] = t1; cnt[2] = t2; cnt[3] = t3; }
    const int b1 = (t0 + 127) & ~127;
    const int b2 = b1 + ((t1 + 127) & ~127);
    const int b3 = b2 + ((t2 + 127) & ~127);
    int r0 = sc[tid][0] - l0;
    int r1 = b1 + sc[tid][1] - l1;
    int r2 = b2 + sc[tid][2] - l2;
    int r3 = b3 + sc[tid][3] - l3;
    #pragma unroll
    for (int i = 0; i < 8; i++) {
        const int t = tid * 8 + i;
        const int a = ep[i] & 15, b = (ep[i] >> 4) & 15;
        const int ra = (a == 0) ? r0++ : (a == 1) ? r1++ : (a == 2) ? r2++ : r3++;
        rowtok[ra] = t; tok2row[t * 2] = ra;
        const int rb = (b == 0) ? r0++ : (b == 1) ? r1++ : (b == 2) ? r2++ : r3++;
        rowtok[rb] = t; tok2row[t * 2 + 1] = rb;
    }
}

// ---------------------------------------------------------------------------
// bf16 MFMA GEMM: C[M,N] = A[M,K] * Bt[N,K]^T. 128x128 tile, 4 waves, BK=64.
// DB=1: double-buffered LDS (64 KB) with counted-wait prefetch loop (for
// grid-starved QKV/Wo). DB=0: single buffer (FF1/FF2 keep >=3 blocks/CU).
// Staging swizzle: col group (lane&7)^(row&7) on the GLOBAL source side,
// mirrored on fragment reads -> conflict-free b128 (LDS dest stays linear).
// modes: 0 QKV (LDS-repacked Q/K row stores + V transpose-through-LDS),
// 2 FF1 compact, 3 Wo split-K partials, 4 FF2 compact.
// swz: 0 3D grid; 1 FF1 XCD map; 2 QKV XCD-chunked flat;
//  3: FF2 flat 768 (split-K x2): xcd=fid&7 -> e=xcd>>1, z=xcd&1;
//     r=fid>>3 (0..95): bx=r%6, by=r/6 (16 m-tiles covers cnt<=2048)
//     -> each XCD owns ONE (e,z) B-slice (2.36 MB, L2-resident)
// ---------------------------------------------------------------------------
template<int DB>
__global__ __launch_bounds__(256) void gemm_bt_kernel(
    const u16* __restrict__ A, int lda, long aZ,
    const u16* __restrict__ Bt, int ldb, long bZ,
    int K, int mode, int swz,
    float* __restrict__ outF, u16* __restrict__ outH,
    u16* __restrict__ outH2, u16* __restrict__ outH3,
    int ldc, long cZ,
    const float* __restrict__ biasF, int biasZ,
    const int* __restrict__ rowtok, const int* __restrict__ cntp,
    const float* __restrict__ comb)
{
    __shared__ __align__(16) u16 As[(DB ? 2 : 1) * 128 * 64];
    __shared__ __align__(16) u16 Bs[(DB ? 2 : 1) * 128 * 64];
    const int tid = threadIdx.x;
    int bx, by, z, e = 0, baseE = 0;
    if (swz == 3) {
        const int fid = blockIdx.x;
        const int xcd = fid & 7; const int r = fid >> 3;
        bx = r % 6; by = r / 6;
        e = xcd >> 1; z = xcd & 1;
    } else if (swz == 1) {
        const int fid = blockIdx.x;
        const int xcd = fid & 7; const int r = fid >> 3;
        const int ne = xcd * 12 + (r % 12);
        by = r / 12; bx = ne % 24; e = ne / 24; z = e;
    } else if (swz == 2) {
        // QKV flat 288: each XCD owns 36 consecutive (bx,by) blocks (by-major)
        const int fid = blockIdx.x;
        const int g = (fid & 7) * 36 + (fid >> 3);
        by = g & 15; bx = g >> 4; z = 0;
    } else {
        bx = blockIdx.x; by = blockIdx.y; z = blockIdx.z;
    }
    if (mode == 2 || mode == 4) {
        const int q0 = (cntp[0] + 127) & ~127;
        const int q1 = (cntp[1] + 127) & ~127;
        const int q2 = (cntp[2] + 127) & ~127;
        baseE = (e > 0 ? q0 : 0) + (e > 1 ? q1 : 0) + (e > 2 ? q2 : 0);
        if (by * 128 >= cntp[e]) return;   // uniform per block: safe early-exit
    }
    const int m0 = by * 128, n0 = bx * 128;
    const u16* Ab = A + (size_t)z * aZ;
    const u16* Bb = Bt + (size_t)z * bZ;
    if (mode == 4) {
        Ab += (size_t)baseE * lda;
        Bb += (size_t)e * ((size_t)DD * FFD);
    }

    const int wave = tid >> 6, lane = tid & 63;
    const int wm = (wave & 1) * 64, wn = (wave >> 1) * 64;
    const int fm = lane & 15;
    const int g  = lane >> 4;

    // staging: wave w covers tile rows [w*32, w*32+32); 4 instrs per operand,
    // instr i covers rows +[i*8, i*8+8). XOR col-group swizzle on global side.
    const int lr8 = lane >> 3;
    const int cg  = ((lane & 7) ^ lr8) * 8;   // swizzled global col (u16)
    const u16 *aG[4], *bG[4];
    u16 *aL[4], *bL[4];
    #pragma unroll
    for (int i = 0; i < 4; i++) {
        const int rr = wave * 32 + i * 8 + lr8;
        int arow;
        if (mode == 2) arow = rowtok[baseE + m0 + rr];
        else           arow = m0 + rr;
        aG[i] = Ab + (size_t)arow * lda + cg;
        bG[i] = Bb + (size_t)(n0 + rr) * ldb + cg;
        aL[i] = &As[(wave * 32 + i * 8) * 64];
        bL[i] = &Bs[(wave * 32 + i * 8) * 64];
    }

#define STAGE(B, KO) do {                                                      \
        const int _o = (B) * (128 * 64);                                       \
        _Pragma("unroll")                                                      \
        for (int _i = 0; _i < 4; _i++) ASYNC16(aG[_i] + (KO), aL[_i] + _o);    \
        _Pragma("unroll")                                                      \
        for (int _i = 0; _i < 4; _i++) ASYNC16(bG[_i] + (KO), bL[_i] + _o);    \
    } while (0)

    // fragment reads: global col g*8 + ks*32 lives at LDS group
    // ((g + ks*4) ^ (row&7)); row&7 == fm&7 for rows wm+i*16+fm
    const int c0 = ((g    ) ^ (fm & 7)) * 8;
    const int c1 = ((g + 4) ^ (fm & 7)) * 8;
    const u16* pa[4]; const u16* pb[4];
    #pragma unroll
    for (int i = 0; i < 4; i++) {
        pa[i] = &As[(wm + i * 16 + fm) * 64];
        pb[i] = &Bs[(wn + i * 16 + fm) * 64];
    }

    f32x4 acc[4][4] = {};
    int buf = 0;
    if (DB) STAGE(0, 0);

    for (int k0 = 0; k0 < K; k0 += 64) {
        if (DB) {
            asm volatile("s_waitcnt vmcnt(0)" ::: "memory");
            __builtin_amdgcn_s_barrier();
            __builtin_amdgcn_sched_barrier(0);
            if (k0 + 64 < K) STAGE(buf ^ 1, k0 + 64);
        } else {
            STAGE(0, k0);
            __syncthreads();
        }
        const int bo = DB ? buf * (128 * 64) : 0;
        #pragma unroll
        for (int ks = 0; ks < 2; ks++) {
            const int cc = bo + (ks ? c1 : c0);
            bf16x8 af[4], bf[4];
            #pragma unroll
            for (int i = 0; i < 4; i++)
                af[i] = *reinterpret_cast<const bf16x8*>(pa[i] + cc);
            #pragma unroll
            for (int j = 0; j < 4; j++)
                bf[j] = *reinterpret_cast<const bf16x8*>(pb[j] + cc);
            #pragma unroll
            for (int i = 0; i < 4; i++)
                #pragma unroll
                for (int j = 0; j < 4; j++)
                    acc[i][j] = MFMA16(af[i], bf[j], acc[i][j]);
        }
        if (DB) buf ^= 1;
        else    __syncthreads();
    }
    if (DB) __syncthreads();
#undef STAGE

    // C/D layout: col = lane&15, row = (lane>>4)*4 + reg   [m89-verified]
    const int cn = lane & 15, cr = (lane >> 4) * 4;

    if (mode == 0) {
        // LDS-repacked epilogue, 4 passes x 32 rows.
        const int which = (n0 >= 1536) ? 2 : (n0 >= 768 ? 1 : 0);
        const int nb = n0 - which * 768;
        u16* outP = (which == 0) ? outH : (which == 1) ? outH2 : outH3;
        u16* Cs = As;
        #pragma unroll
        for (int i = 0; i < 4; i++) {
            if (i) __syncthreads();
            #pragma unroll
            for (int j = 0; j < 4; j++) {
                const int n = n0 + wn + j * 16 + cn;
                const float bias = biasF[n];
                #pragma unroll
                for (int r = 0; r < 4; r++) {
                    Cs[((wave & 1) * 16 + cr + r) * 128 + wn + j * 16 + cn] =
                        f2us(acc[i][j][r] + bias);
                }
            }
            __syncthreads();
            if (which < 2) {
                // Q/K: row stores, 16 u16 per thread within one head's 64-run
                const int lr2 = tid >> 3, c2 = (tid & 7) * 16;
                const int m2 = m0 + (lr2 >> 4) * 64 + i * 16 + (lr2 & 15);
                const int bb2 = m2 >> 10, t2 = m2 & 1023;
                const int hh = (nb + c2) >> 6, d0 = (nb + c2) & 63;
                u16* dst = outP + (((size_t)(bb2 * HH + hh) * TT + t2) << 6) + d0;
                *reinterpret_cast<uint4*>(dst) =
                    *reinterpret_cast<const uint4*>(&Cs[lr2 * 128 + c2]);
                *reinterpret_cast<uint4*>(dst + 8) =
                    *reinterpret_cast<const uint4*>(&Cs[lr2 * 128 + c2 + 8]);
            } else {
                // V: transpose through LDS; 16B stores along t.
                const int nl = tid >> 1, half = tid & 1;
                const int hh = (nb + nl) >> 6, d = (nb + nl) & 63;
                #pragma unroll
                for (int seg = 0; seg < 2; seg++) {
                    u16 o[8];
                    #pragma unroll
                    for (int k = 0; k < 8; k++)
                        o[k] = Cs[(seg * 16 + half * 8 + k) * 128 + nl];
                    const int t0 = m0 + seg * 64 + i * 16 + half * 8;
                    const int bb2 = t0 >> 10, tt2 = t0 & 1023;
                    u16* dst = outP + (((size_t)(bb2 * HH + hh) * HD + d) << 10) + tt2;
                    *reinterpret_cast<uint4*>(dst) = *reinterpret_cast<uint4*>(o);
                }
            }
        }
        return;
    }

    if (mode == 2) {
        // LDS-repacked epilogue: 4 passes x 32 rows, dwordx4 coalesced stores
        u16* Cs = As;
        #pragma unroll
        for (int i = 0; i < 4; i++) {
            if (i) __syncthreads();
            int tokr[4]; float combr[4];
            #pragma unroll
            for (int r = 0; r < 4; r++)
                tokr[r] = rowtok[baseE + m0 + wm + i * 16 + cr + r];
            #pragma unroll
            for (int r = 0; r < 4; r++)
                combr[r] = comb[(size_t)tokr[r] * NE + z];
            #pragma unroll
            for (int j = 0; j < 4; j++) {
                const int n = n0 + wn + j * 16 + cn;
                const float bias = biasF[(size_t)z * biasZ + n];
                #pragma unroll
                for (int r = 0; r < 4; r++) {
                    float y = fmaxf(acc[i][j][r] + bias, 0.f) * combr[r];
                    Cs[((wave & 1) * 16 + cr + r) * 128 + wn + j * 16 + cn] = f2us(y);
                }
            }
            __syncthreads();
            const int lr2 = tid >> 3, c2 = (tid & 7) * 16;
            const int m2 = m0 + (lr2 >> 4) * 64 + i * 16 + (lr2 & 15);
            u16* dst = outH + (size_t)(baseE + m2) * ldc + n0 + c2;
            *reinterpret_cast<uint4*>(dst) =
                *reinterpret_cast<const uint4*>(&Cs[lr2 * 128 + c2]);
            *reinterpret_cast<uint4*>(dst + 8) =
                *reinterpret_cast<const uint4*>(&Cs[lr2 * 128 + c2 + 8]);
        }
        return;
    }

    #pragma unroll
    for (int i = 0; i < 4; i++) {
        #pragma unroll
        for (int j = 0; j < 4; j++) {
            const int n = n0 + wn + j * 16 + cn;
            #pragma unroll
            for (int r = 0; r < 4; r++) {
                const int m = m0 + wm + i * 16 + cr + r;
                // mode 3 (baseE=0) and mode 4 (compact rows)
                float* basep = outF + (size_t)z * cZ;
                basep[(size_t)(baseE + m) * ldc + n] = acc[i][j][r];
            }
        }
    }
}

// ---------------------------------------------------------------------------
// MFMA attention. Block = (qt 16 rows, head). 4 waves, QBLK=16.
// XCD-affine map (each XCD owns 3 heads; K/V L2-resident, FETCH 4.7 MB).
// Structure closed at ~54 us: latency-stall-bound at the 16-waves/CU cap
// imposed by the 64-AGPR accumulator (R6-R10 evidence).
// ---------------------------------------------------------------------------
#define PSTR 1032  // u16 stride: byte stride 2064 (16B aligned), dw 516 ≡ 4 mod 8 -> conflict-free b128
__global__ __launch_bounds__(256, 3) void attn_mfma_kernel(
    const u16* __restrict__ Qh, const u16* __restrict__ Kh,
    const u16* __restrict__ VT, const float* __restrict__ gamma_p,
    u16* __restrict__ attn_out)
{
    __shared__ __align__(16) u16 P[16 * PSTR];
    __shared__ __align__(16) float wred[4][16][4];
    __shared__ __align__(16) float dred[16][4];

    const int fid = blockIdx.x;
    const int xcd = fid & 7, rr = fid >> 3;
    const int bh = xcd * 3 + (rr >> 6);     // 24 heads: 3 per XCD
    const int qt = rr & 63;
    const int b = bh / HH, h = bh - b * HH;
    const int tid = threadIdx.x, wave = tid >> 6, lane = tid & 63;
    const int g = lane >> 4, fm = lane & 15;
    const float gamma = gamma_p[0];
    const int m0 = qt * 16;
    const u16* Qp = Qh + (size_t)bh * TT * HD;
    const u16* Kp = Kh + (size_t)bh * TT * HD;
    const u16* Vp = VT + (size_t)bh * HD * TT;

    bf16x8 af[2];
    #pragma unroll
    for (int ks = 0; ks < 2; ks++)
        af[ks] = *reinterpret_cast<const bf16x8*>(
            Qp + (size_t)(m0 + fm) * HD + ks * 32 + g * 8);

    const int n0w = wave * 256;
    f32x4 acc[16] = {};
    #pragma unroll
    for (int nj = 0; nj < 16; nj++) {
        const u16* kp = Kp + (size_t)(n0w + nj * 16 + fm) * HD + g * 8;
        bf16x8 b0 = *reinterpret_cast<const bf16x8*>(kp);
        bf16x8 b1 = *reinterpret_cast<const bf16x8*>(kp + 32);
        acc[nj] = MFMA16(af[0], b0, acc[nj]);
        acc[nj] = MFMA16(af[1], b1, acc[nj]);
    }

    // ---- per-wave row stats -> LDS ----
    #pragma unroll
    for (int r = 0; r < 4; r++) {
        float s1 = 0.f, s2 = 0.f, mx = -3.4e38f, mn = 3.4e38f;
        #pragma unroll
        for (int nj = 0; nj < 16; nj++) {
            float v = acc[nj][r];
            s1 += v; s2 = fmaf(v, v, s2);
            mx = fmaxf(mx, v); mn = fminf(mn, v);
        }
        #pragma unroll
        for (int msk = 1; msk < 16; msk <<= 1) {
            s1 += __shfl_xor(s1, msk);
            s2 += __shfl_xor(s2, msk);
            mx = fmaxf(mx, __shfl_xor(mx, msk));
            mn = fminf(mn, __shfl_xor(mn, msk));
        }
        if (fm == 0) {
            const int row = g * 4 + r;
            wred[wave][row][0] = s1; wred[wave][row][1] = s2;
            wred[wave][row][2] = mx; wred[wave][row][3] = mn;
        }
    }
    __syncthreads();   // barrier 1: wred complete

    // ---- inline combine + softmax (a/cm are loop-local temps) ----
    #pragma unroll
    for (int r = 0; r < 4; r++) {
        const int row = g * 4 + r;
        float s1 = 0.f, s2 = 0.f, mx = -3.4e38f, mn = 3.4e38f;
        #pragma unroll
        for (int w = 0; w < 4; w++) {
            float4 t = *reinterpret_cast<const float4*>(&wred[w][row][0]);
            s1 += t.x; s2 += t.y;
            mx = fmaxf(mx, t.z); mn = fminf(mn, t.w);
        }
        float var = (s2 - s1 * s1 * (1.f / TT)) * (1.f / (TT - 1));
        var = fmaxf(var, 0.f);
        const float a = gamma / (sqrtf(var) + 8e-5f);
        const float cm = (a >= 0.f) ? a * mx : a * mn;
        float dp = 0.f;
        #pragma unroll
        for (int nj = 0; nj < 16; nj++) {
            float p = __expf(fmaf(a, acc[nj][r], -cm));
            u16 pb = f2us(p);
            dp += us2f(pb);
            P[row * PSTR + n0w + nj * 16 + fm] = pb;
        }
        #pragma unroll
        for (int msk = 1; msk < 16; msk <<= 1) dp += __shfl_xor(dp, msk);
        if (fm == 0) dred[row][wave] = dp;
    }
    __syncthreads();   // barrier 2: P + dred complete

    // ---- PV (direct loads) ----
    f32x4 oacc = {};
    #pragma unroll 8
    for (int ks = 0; ks < 32; ks++) {
        bf16x8 bv = *reinterpret_cast<const bf16x8*>(
            Vp + (size_t)(wave * 16 + fm) * TT + ks * 32 + g * 8);
        bf16x8 a0 = *reinterpret_cast<const bf16x8*>(&P[(size_t)fm * PSTR + ks * 32 + g * 8]);
        oacc = MFMA16(a0, bv, oacc);
    }

    // ---- epilogue: dinv folded here ----
    #pragma unroll
    for (int r = 0; r < 4; r++) {
        const int row = g * 4 + r;
        float4 dv = *reinterpret_cast<const float4*>(&dred[row][0]);
        const float dinv = 1.f / (dv.x + dv.y + dv.z + dv.w);
        const int t = m0 + row;
        attn_out[((size_t)(b * TT + t)) * DD + h * HD + wave * 16 + fm] =
            f2us(oacc[r] * dinv);
    }
}

// ---------------------------------------------------------------------------
// LN1 fused + gate: layernorm -> x fp32 + xh bf16; gate on in-register
// post-LN values; thread-0 softmax/top-2 -> comb, epack.
// ---------------------------------------------------------------------------
__global__ __launch_bounds__(256) void ln1_kernel(
    const float* __restrict__ p0, const float* __restrict__ p1,
    const float* __restrict__ p2, const float* __restrict__ p3,
    const float* __restrict__ src, const float* __restrict__ bo,
    const float* __restrict__ g, const float* __restrict__ bta,
    const float* __restrict__ Wg, const float* __restrict__ bg,
    float* __restrict__ outF, u16* __restrict__ outH,
    float* __restrict__ comb, int* __restrict__ epack)
{
    const int row = blockIdx.x, tid = threadIdx.x;
    __shared__ float red[256];
    __shared__ float gred[4][4];
    const size_t base = (size_t)row * DD;
    float v[3];
    #pragma unroll
    for (int i = 0; i < 3; i++) {
        int c = tid + i * 256;
        v[i] = p0[base + c] + p1[base + c] + p2[base + c] + p3[base + c]
             + src[base + c] + bo[c];
    }
    float s = v[0] + v[1] + v[2];
    red[tid] = s; __syncthreads();
    #pragma unroll
    for (int o = 128; o > 0; o >>= 1) { if (tid < o) red[tid] += red[tid + o]; __syncthreads(); }
    const float mean = red[0] * (1.f / 768.f);
    __syncthreads();
    float qv = 0.f;
    #pragma unroll
    for (int i = 0; i < 3; i++) { float d = v[i] - mean; qv += d * d; }
    red[tid] = qv; __syncthreads();
    #pragma unroll
    for (int o = 128; o > 0; o >>= 1) { if (tid < o) red[tid] += red[tid + o]; __syncthreads(); }
    const float var = red[0] * (1.f / 768.f);
    const float rs = rsqrtf(var + 1e-5f);
    float ga0 = 0.f, ga1 = 0.f, ga2 = 0.f, ga3 = 0.f;
    #pragma unroll
    for (int i = 0; i < 3; i++) {
        int c = tid + i * 256;
        float o = (v[i] - mean) * rs * g[c] + bta[c];
        outF[base + c] = o;
        outH[base + c] = f2us(o);
        ga0 = fmaf(o, Wg[c], ga0);
        ga1 = fmaf(o, Wg[DD + c], ga1);
        ga2 = fmaf(o, Wg[2 * DD + c], ga2);
        ga3 = fmaf(o, Wg[3 * DD + c], ga3);
    }
    #pragma unroll
    for (int off = 32; off > 0; off >>= 1) {
        ga0 += __shfl_down(ga0, off, 64);
        ga1 += __shfl_down(ga1, off, 64);
        ga2 += __shfl_down(ga2, off, 64);
        ga3 += __shfl_down(ga3, off, 64);
    }
    const int wave = tid >> 6, lane = tid & 63;
    if (lane == 0) {
        gred[wave][0] = ga0; gred[wave][1] = ga1;
        gred[wave][2] = ga2; gred[wave][3] = ga3;
    }
    __syncthreads();
    if (tid == 0) {
        float gg[NE];
        #pragma unroll
        for (int e = 0; e < NE; e++)
            gg[e] = gred[0][e] + gred[1][e] + gred[2][e] + gred[3][e] + bg[e];
        float m = -1e30f;
        #pragma unroll
        for (int e = 0; e < NE; e++) m = fmaxf(m, gg[e]);
        float ex[NE], ssum = 0.f;
        #pragma unroll
        for (int e = 0; e < NE; e++) { ex[e] = __expf(gg[e] - m); ssum += ex[e]; }
        #pragma unroll
        for (int e = 0; e < NE; e++) ex[e] /= ssum;
        int e1 = 0;
        #pragma unroll
        for (int e = 1; e < NE; e++) if (ex[e] > ex[e1]) e1 = e;
        int e2 = -1;
        #pragma unroll
        for (int e = 0; e < NE; e++) if (e != e1 && (e2 < 0 || ex[e] > ex[e2])) e2 = e;
        float c[NE] = {0.f, 0.f, 0.f, 0.f};
        c[e1] = ex[e1]; c[e2] = ex[e2];
        #pragma unroll
        for (int e = 0; e < NE; e++) comb[(size_t)row * NE + e] = c[e];
        epack[row] = e1 | (e2 << 4);
    }
}

// ---------------------------------------------------------------------------
// LN2 (compact, 2 slabs): t = x + sum_{z<2} sum_{i<2} pslab[z][tok2row[t,i]]
// + comb*b2; layernorm -> out.
// ---------------------------------------------------------------------------
__global__ __launch_bounds__(256) void ln2_kernel(
    const float* __restrict__ x, const float* __restrict__ pslab,
    const int* __restrict__ tok2row,
    const float* __restrict__ comb, const float* __restrict__ b2,
    const float* __restrict__ g, const float* __restrict__ bta,
    float* __restrict__ outF)
{
    const int row = blockIdx.x, tid = threadIdx.x;
    __shared__ float red[256];
    const size_t base = (size_t)row * DD;
    const int r0 = tok2row[row * 2], r1 = tok2row[row * 2 + 1];
    const float* q0 = pslab + (size_t)r0 * DD;
    const float* q1 = pslab + (size_t)r1 * DD;
    const float c0 = comb[row * NE + 0], c1 = comb[row * NE + 1];
    const float c2 = comb[row * NE + 2], c3 = comb[row * NE + 3];
    float v[3];
    #pragma unroll
    for (int i = 0; i < 3; i++) {
        int c = tid + i * 256;
        float t = x[base + c];
        t += q0[c] + q0[SLABZ + c];
        t += q1[c] + q1[SLABZ + c];
        t = fmaf(c0, b2[c], t);
        t = fmaf(c1, b2[DD + c], t);
        t = fmaf(c2, b2[2 * DD + c], t);
        t = fmaf(c3, b2[3 * DD + c], t);
        v[i] = t;
    }
    float s = v[0] + v[1] + v[2];
    red[tid] = s; __syncthreads();
    #pragma unroll
    for (int o = 128; o > 0; o >>= 1) { if (tid < o) red[tid] += red[tid + o]; __syncthreads(); }
    const float mean = red[0] * (1.f / 768.f);
    __syncthreads();
    float qv = 0.f;
    #pragma unroll
    for (int i = 0; i < 3; i++) { float d = v[i] - mean; qv += d * d; }
    red[tid] = qv; __syncthreads();
    #pragma unroll
    for (int o = 128; o > 0; o >>= 1) { if (tid < o) red[tid] += red[tid + o]; __syncthreads(); }
    const float var = red[0] * (1.f / 768.f);
    const float rs = rsqrtf(var + 1e-5f);
    #pragma unroll
    for (int i = 0; i < 3; i++) {
        int c = tid + i * 256;
        outF[base + c] = (v[i] - mean) * rs * g[c] + bta[c];
    }
}

extern "C" void kernel_launch(void* const* d_in, const int* in_sizes, int n_in,
                              void* d_out, int out_size, void* d_ws, size_t ws_size,
                              hipStream_t stream)
{
    const float* src  = (const float*)d_in[0];
    const float* Wq   = (const float*)d_in[2];  const float* bq = (const float*)d_in[3];
    const float* Wk   = (const float*)d_in[4];  const float* bk = (const float*)d_in[5];
    const float* Wv   = (const float*)d_in[6];  const float* bv = (const float*)d_in[7];
    const float* Wo   = (const float*)d_in[8];  const float* bo = (const float*)d_in[9];
    const float* gam  = (const float*)d_in[10];
    const float* ln1g = (const float*)d_in[11]; const float* ln1b = (const float*)d_in[12];
    const float* ln2g = (const float*)d_in[13]; const float* ln2b = (const float*)d_in[14];
    const float* Wg   = (const float*)d_in[15]; const float* bg = (const float*)d_in[16];
    const float* W1   = (const float*)d_in[17]; const float* b1 = (const float*)d_in[18];
    const float* W2   = (const float*)d_in[19]; const float* b2 = (const float*)d_in[20];
    (void)ws_size; (void)in_sizes; (void)n_in; (void)out_size;

    char* ws = (char*)d_ws;
    u16*   W1T  = (u16*)(ws);
    float* wop  = (float*)(ws + 18874368);
    float* pslab= (float*)(ws);                        // 2 slabs x 14.2 MB (after FF1)
    u16*   W2T  = (u16*)(ws + 56623104);               // 18,874,368 (live through FF2)
    u16*   hb   = (u16*)(ws + 75497472);               // 28,311,552 compact FF1 out [CROWS][3072]
    float* x    = (float*)(ws + 103809024);            //  6,291,456
    u16*   xh   = (u16*)(ws + 110100480);              //  3,145,728
    float* comb = (float*)(ws + 113246208);            //     32,768
    float* bqkv = (float*)(ws + 113278976);            //      9,216
    int*   cnt    = (int*)(ws + 113288192);            //         64
    int*   rowtok = (int*)(ws + 113288256);            //     18,432 (CROWS)
    int*   epack  = (int*)(ws + 113306688);            //      8,192
    int*   tok2row= (int*)(ws + 113323072);            //     16,384
    // attn-phase aliases inside hb region (all dead before FF1 writes hb)
    char* H = ws + 75497472;
    u16*   Qh     = (u16*)(H);
    u16*   Kh     = (u16*)(H + 3145728);
    u16*   VTh    = (u16*)(H + 6291456);
    u16*   src_h  = (u16*)(H + 9437184);
    u16*   attn_h = (u16*)(H + 12582912);
    u16*   WqkvH  = (u16*)(H + 15728640);
    u16*   WoH    = (u16*)(H + 19267584);
    const long PZ = (long)NTOK * DD;

    // ---- fused conversions (2 launches total) ----
    convert5_kernel<<<1921, 256, 0, stream>>>(
        src, Wq, Wk, Wv, Wo, bq, bk, bv, src_h, WqkvH, WoH, bqkv);
    transpose_all_kernel<<<18432, 256, 0, stream>>>(W1, W2, W1T, W2T);

    // ---- QKV (dbuf prefetch, XCD-chunked flat 288) ----
    gemm_bt_kernel<1><<<dim3(288, 1, 1), 256, 0, stream>>>(
        src_h, DD, 0, WqkvH, DD, 0, DD, 0, 2,
        nullptr, Qh, Kh, VTh, 0, 0, bqkv, 0, nullptr, nullptr, nullptr);

    // ---- attention (MFMA, XCD-affine head map) ----
    attn_mfma_kernel<<<dim3(1536, 1, 1), 256, 0, stream>>>(
        Qh, Kh, VTh, gam, attn_h);

    // ---- Wo projection split-K x4 (dbuf prefetch) -> fp32 partials ----
    gemm_bt_kernel<1><<<dim3(DD / 128, NTOK / 128, 4), 256, 0, stream>>>(
        attn_h, DD, 192L, WoH, DD, 192L, 192, 3, 0,
        wop, nullptr, nullptr, nullptr, DD, PZ, nullptr, 0, nullptr, nullptr, nullptr);

    // ---- LN1 + fused gate (no atomics) ----
    ln1_kernel<<<NTOK, 256, 0, stream>>>(
        wop, wop + PZ, wop + 2 * PZ, wop + 3 * PZ, src, bo,
        ln1g, ln1b, Wg, bg, x, xh, comb, epack);

    // ---- deterministic slot assignment (single-block prefix scan) ----
    scan_build_kernel<<<1, 256, 0, stream>>>(epack, cnt, rowtok, tok2row);

    // ---- FF1 compact (top-2 only), single-buffer (occupancy) ----
    gemm_bt_kernel<0><<<dim3(1536, 1, 1), 256, 0, stream>>>(
        xh, DD, 0, W1T, DD, (long)FFD * DD, DD, 2, 1,
        nullptr, hb, nullptr, nullptr, FFD, 0, b1, FFD, rowtok, cnt, comb);

    // ---- FF2 compact: per-expert K=3072 split-K x2 (K=1536/slice, 24
    //      BK-iters), flat 768: each XCD owns ONE (e,z) B-slice (2.36 MB,
    //      L2-resident); partial traffic halved vs x4 ----
    gemm_bt_kernel<0><<<dim3(768, 1, 1), 256, 0, stream>>>(
        hb, FFD, 1536L, W2T, FFD, 1536L, 1536, 4, 3,
        pslab, nullptr, nullptr, nullptr, DD, SLABZ, nullptr, 0, rowtok, cnt, nullptr);

    // ---- LN2 (x + gathered 2-slab partials + comb*b2, then layernorm) ----
    ln2_kernel<<<NTOK, 256, 0, stream>>>(
        x, pslab, tok2row, comb, b2, ln2g, ln2b, (float*)d_out);
}

// Round 12
// 334.886 us; speedup vs baseline: 1.0615x; 1.0177x over previous
//
#include <hip/hip_runtime.h>

typedef unsigned short u16;
typedef short bf16x8 __attribute__((ext_vector_type(8)));
typedef float f32x4 __attribute__((ext_vector_type(4)));

#define BB 2
#define TT 1024
#define DD 768
#define HH 12
#define HD 64
#define FFD 3072
#define NE 4
#define NTOK (BB*TT)
// compact MoE row space: sum_e ceil(cnt[e]/128)*128 <= 4096 + 4*127 = 4604
#define CROWS 4608
#define SLABZ 3538944L   // CROWS*DD elements per FF2 partial slab

#define MFMA16(a, b, c) __builtin_amdgcn_mfma_f32_16x16x32_bf16((a), (b), (c), 0, 0, 0)

#define ASYNC16(gsrc, ldst)                                                    \
    __builtin_amdgcn_global_load_lds(                                          \
        (const __attribute__((address_space(1))) void*)(gsrc),                 \
        (__attribute__((address_space(3))) void*)(ldst), 16, 0, 0)

__device__ __forceinline__ float us2f(u16 u) {
    return __uint_as_float(((unsigned int)u) << 16);
}
__device__ __forceinline__ u16 f2us(float f) {
    unsigned int x = __float_as_uint(f);
    x += 0x7fffu + ((x >> 16) & 1u);
    return (u16)(x >> 16);
}

// ---------------------------------------------------------------------------
// Single fused conversion kernel (one launch for ALL preprocessing):
// bid < 1920:       flat fp32->bf16 of src + Wq/Wk/Wv/Wo
// bid == 1920:      bias concat bq|bk|bv -> bqkv
// 1921..11136:      W1[e][768][3072] -> W1T[e][3072][768] (tiles 96x24 per e)
// 11137..20352:     W2[e][3072][768] -> W2T[e][768][3072] (tiles 24x96 per e)
// ---------------------------------------------------------------------------
__global__ __launch_bounds__(256) void convert_all_kernel(
    const float* __restrict__ src, const float* __restrict__ wq,
    const float* __restrict__ wk, const float* __restrict__ wv,
    const float* __restrict__ wo,
    const float* __restrict__ bq, const float* __restrict__ bk,
    const float* __restrict__ bv,
    const float* __restrict__ W1, const float* __restrict__ W2,
    u16* __restrict__ src_h, u16* __restrict__ wqkv_h, u16* __restrict__ wo_h,
    float* __restrict__ bqkv, u16* __restrict__ W1T, u16* __restrict__ W2T)
{
    const int bid = blockIdx.x, tid = threadIdx.x;
    if (bid < 1920) {
        int i = bid * 256 + tid;
        const float* in; u16* out; int off;
        if (i < 196608) { in = src; out = src_h; off = i; }
        else {
            int j = i - 196608; int w = j / 73728; off = j - w * 73728;
            in = (w == 0) ? wq : (w == 1) ? wk : (w == 2) ? wv : wo;
            out = (w < 3) ? wqkv_h + (size_t)w * (DD * DD) : wo_h;
        }
        const float4* p = reinterpret_cast<const float4*>(in) + (size_t)off * 2;
        float4 a = p[0], b = p[1];
        u16 o[8] = {f2us(a.x), f2us(a.y), f2us(a.z), f2us(a.w),
                    f2us(b.x), f2us(b.y), f2us(b.z), f2us(b.w)};
        *reinterpret_cast<uint4*>(out + (size_t)off * 8) = *reinterpret_cast<uint4*>(o);
        return;
    }
    if (bid == 1920) {
        for (int i = tid; i < 3 * DD; i += 256) {
            float v = (i < DD) ? bq[i] : (i < 2 * DD) ? bk[i - DD] : bv[i - 2 * DD];
            bqkv[i] = v;
        }
        return;
    }
    // transpose section
    __shared__ float tile[32][33];
    const int tb = bid - 1921;
    const float* s; u16* d; int C, dstStride, c0, r0;
    if (tb < 9216) {
        const int e = tb / 2304, rem = tb % 2304;
        c0 = (rem % 96) * 32; r0 = (rem / 96) * 32;
        C = FFD; dstStride = DD;
        s = W1 + (size_t)e * DD * FFD; d = W1T + (size_t)e * FFD * DD;
    } else {
        const int b2 = tb - 9216;
        const int e = b2 / 2304, rem = b2 % 2304;
        c0 = (rem % 24) * 32; r0 = (rem / 24) * 32;
        C = DD; dstStride = FFD;
        s = W2 + (size_t)e * FFD * DD; d = W2T + (size_t)e * FFD * DD;
    }
    {
        const int r = tid >> 3, cs = (tid & 7) * 4;
        float4 v = *reinterpret_cast<const float4*>(&s[(size_t)(r0 + r) * C + c0 + cs]);
        tile[r][cs] = v.x; tile[r][cs + 1] = v.y;
        tile[r][cs + 2] = v.z; tile[r][cs + 3] = v.w;
    }
    __syncthreads();
    {
        const int c = tid >> 3, rs = (tid & 7) * 4;
        u16 o[4] = {f2us(tile[rs][c]), f2us(tile[rs + 1][c]),
                    f2us(tile[rs + 2][c]), f2us(tile[rs + 3][c])};
        *reinterpret_cast<uint2*>(&d[(size_t)(c0 + c) * dstStride + r0 + rs]) =
            *reinterpret_cast<uint2*>(o);
    }
}

// ---------------------------------------------------------------------------
// Deterministic compact-slot assignment: single block, Hillis-Steele prefix
// scan over 2048 tokens (8 tokens/thread, 2 entries each).
// ---------------------------------------------------------------------------
__global__ __launch_bounds__(256) void scan_build_kernel(
    const int* __restrict__ epack, int* __restrict__ cnt,
    int* __restrict__ rowtok, int* __restrict__ tok2row)
{
    __shared__ int sc[256][4];
    const int tid = threadIdx.x;
    for (int i = tid; i < CROWS; i += 256) rowtok[i] = 0;
    int ep[8];
    int l0 = 0, l1 = 0, l2 = 0, l3 = 0;
    #pragma unroll
    for (int i = 0; i < 8; i++) {
        const int v = epack[tid * 8 + i];
        ep[i] = v;
        const int a = v & 15, b = (v >> 4) & 15;
        l0 += (a == 0) + (b == 0);
        l1 += (a == 1) + (b == 1);
        l2 += (a == 2) + (b == 2);
        l3 += (a == 3) + (b == 3);
    }
    sc[tid][0] = l0; sc[tid][1] = l1; sc[tid][2] = l2; sc[tid][3] = l3;
    __syncthreads();
    for (int off = 1; off < 256; off <<= 1) {
        int v0 = 0, v1 = 0, v2 = 0, v3 = 0;
        if (tid >= off) {
            v0 = sc[tid - off][0]; v1 = sc[tid - off][1];
            v2 = sc[tid - off][2]; v3 = sc[tid - off][3];
        }
        __syncthreads();
        if (tid >= off) {
            sc[tid][0] += v0; sc[tid][1] += v1;
            sc[tid][2] += v2; sc[tid][3] += v3;
        }
        __syncthreads();
    }
    const int t0 = sc[255][0], t1 = sc[255][1], t2 = sc[255][2], t3 = sc[255][3];
    if (tid == 0) { cnt[0] = t0; cnt[1] = t1; cnt[2] = t2; cnt[3] = t3; }
    const int b1 = (t0 + 127) & ~127;
    const int b2 = b1 + ((t1 + 127) & ~127);
    const int b3 = b2 + ((t2 + 127) & ~127);
    int r0 = sc[tid][0] - l0;
    int r1 = b1 + sc[tid][1] - l1;
    int r2 = b2 + sc[tid][2] - l2;
    int r3 = b3 + sc[tid][3] - l3;
    #pragma unroll
    for (int i = 0; i < 8; i++) {
        const int t = tid * 8 + i;
        const int a = ep[i] & 15, b = (ep[i] >> 4) & 15;
        const int ra = (a == 0) ? r0++ : (a == 1) ? r1++ : (a == 2) ? r2++ : r3++;
        rowtok[ra] = t; tok2row[t * 2] = ra;
        const int rb = (b == 0) ? r0++ : (b == 1) ? r1++ : (b == 2) ? r2++ : r3++;
        rowtok[rb] = t; tok2row[t * 2 + 1] = rb;
    }
}

// ---------------------------------------------------------------------------
// bf16 MFMA GEMM: C[M,N] = A[M,K] * Bt[N,K]^T. 128x128 tile, 4 waves, BK=64.
// DB=1: double-buffered LDS (64 KB) with counted-wait prefetch loop (for
// grid-starved QKV/Wo). DB=0: single buffer (FF1/FF2 keep >=3 blocks/CU).
// Staging swizzle: col group (lane&7)^(row&7) on the GLOBAL source side,
// mirrored on fragment reads -> conflict-free b128 (LDS dest stays linear).
// modes: 0 QKV (LDS-repacked Q/K row stores + V transpose-through-LDS),
// 2 FF1 compact, 3 Wo split-K partials, 4 FF2 compact.
// swz: 0 3D grid; 1 FF1 XCD map; 2 QKV XCD-chunked flat;
//  3: FF2 flat 768 (split-K x2): xcd=fid&7 -> e=xcd>>1, z=xcd&1;
//     r=fid>>3: bx=r%6, by=r/6 -> each XCD owns ONE (e,z) B-slice (2.36 MB)
// ---------------------------------------------------------------------------
template<int DB>
__global__ __launch_bounds__(256) void gemm_bt_kernel(
    const u16* __restrict__ A, int lda, long aZ,
    const u16* __restrict__ Bt, int ldb, long bZ,
    int K, int mode, int swz,
    float* __restrict__ outF, u16* __restrict__ outH,
    u16* __restrict__ outH2, u16* __restrict__ outH3,
    int ldc, long cZ,
    const float* __restrict__ biasF, int biasZ,
    const int* __restrict__ rowtok, const int* __restrict__ cntp,
    const float* __restrict__ comb)
{
    __shared__ __align__(16) u16 As[(DB ? 2 : 1) * 128 * 64];
    __shared__ __align__(16) u16 Bs[(DB ? 2 : 1) * 128 * 64];
    const int tid = threadIdx.x;
    int bx, by, z, e = 0, baseE = 0;
    if (swz == 3) {
        const int fid = blockIdx.x;
        const int xcd = fid & 7; const int r = fid >> 3;
        bx = r % 6; by = r / 6;
        e = xcd >> 1; z = xcd & 1;
    } else if (swz == 1) {
        const int fid = blockIdx.x;
        const int xcd = fid & 7; const int r = fid >> 3;
        const int ne = xcd * 12 + (r % 12);
        by = r / 12; bx = ne % 24; e = ne / 24; z = e;
    } else if (swz == 2) {
        // QKV flat 288: each XCD owns 36 consecutive (bx,by) blocks (by-major)
        const int fid = blockIdx.x;
        const int g = (fid & 7) * 36 + (fid >> 3);
        by = g & 15; bx = g >> 4; z = 0;
    } else {
        bx = blockIdx.x; by = blockIdx.y; z = blockIdx.z;
    }
    if (mode == 2 || mode == 4) {
        const int q0 = (cntp[0] + 127) & ~127;
        const int q1 = (cntp[1] + 127) & ~127;
        const int q2 = (cntp[2] + 127) & ~127;
        baseE = (e > 0 ? q0 : 0) + (e > 1 ? q1 : 0) + (e > 2 ? q2 : 0);
        if (by * 128 >= cntp[e]) return;   // uniform per block: safe early-exit
    }
    const int m0 = by * 128, n0 = bx * 128;
    const u16* Ab = A + (size_t)z * aZ;
    const u16* Bb = Bt + (size_t)z * bZ;
    if (mode == 4) {
        Ab += (size_t)baseE * lda;
        Bb += (size_t)e * ((size_t)DD * FFD);
    }

    const int wave = tid >> 6, lane = tid & 63;
    const int wm = (wave & 1) * 64, wn = (wave >> 1) * 64;
    const int fm = lane & 15;
    const int g  = lane >> 4;

    // staging: wave w covers tile rows [w*32, w*32+32); 4 instrs per operand,
    // instr i covers rows +[i*8, i*8+8). XOR col-group swizzle on global side.
    const int lr8 = lane >> 3;
    const int cg  = ((lane & 7) ^ lr8) * 8;   // swizzled global col (u16)
    const u16 *aG[4], *bG[4];
    u16 *aL[4], *bL[4];
    #pragma unroll
    for (int i = 0; i < 4; i++) {
        const int rr = wave * 32 + i * 8 + lr8;
        int arow;
        if (mode == 2) arow = rowtok[baseE + m0 + rr];
        else           arow = m0 + rr;
        aG[i] = Ab + (size_t)arow * lda + cg;
        bG[i] = Bb + (size_t)(n0 + rr) * ldb + cg;
        aL[i] = &As[(wave * 32 + i * 8) * 64];
        bL[i] = &Bs[(wave * 32 + i * 8) * 64];
    }

#define STAGE(B, KO) do {                                                      \
        const int _o = (B) * (128 * 64);                                       \
        _Pragma("unroll")                                                      \
        for (int _i = 0; _i < 4; _i++) ASYNC16(aG[_i] + (KO), aL[_i] + _o);    \
        _Pragma("unroll")                                                      \
        for (int _i = 0; _i < 4; _i++) ASYNC16(bG[_i] + (KO), bL[_i] + _o);    \
    } while (0)

    // fragment reads: global col g*8 + ks*32 lives at LDS group
    // ((g + ks*4) ^ (row&7)); row&7 == fm&7 for rows wm+i*16+fm
    const int c0 = ((g    ) ^ (fm & 7)) * 8;
    const int c1 = ((g + 4) ^ (fm & 7)) * 8;
    const u16* pa[4]; const u16* pb[4];
    #pragma unroll
    for (int i = 0; i < 4; i++) {
        pa[i] = &As[(wm + i * 16 + fm) * 64];
        pb[i] = &Bs[(wn + i * 16 + fm) * 64];
    }

    f32x4 acc[4][4] = {};
    int buf = 0;
    if (DB) STAGE(0, 0);

    for (int k0 = 0; k0 < K; k0 += 64) {
        if (DB) {
            asm volatile("s_waitcnt vmcnt(0)" ::: "memory");
            __builtin_amdgcn_s_barrier();
            __builtin_amdgcn_sched_barrier(0);
            if (k0 + 64 < K) STAGE(buf ^ 1, k0 + 64);
        } else {
            STAGE(0, k0);
            __syncthreads();
        }
        const int bo = DB ? buf * (128 * 64) : 0;
        #pragma unroll
        for (int ks = 0; ks < 2; ks++) {
            const int cc = bo + (ks ? c1 : c0);
            bf16x8 af[4], bf[4];
            #pragma unroll
            for (int i = 0; i < 4; i++)
                af[i] = *reinterpret_cast<const bf16x8*>(pa[i] + cc);
            #pragma unroll
            for (int j = 0; j < 4; j++)
                bf[j] = *reinterpret_cast<const bf16x8*>(pb[j] + cc);
            #pragma unroll
            for (int i = 0; i < 4; i++)
                #pragma unroll
                for (int j = 0; j < 4; j++)
                    acc[i][j] = MFMA16(af[i], bf[j], acc[i][j]);
        }
        if (DB) buf ^= 1;
        else    __syncthreads();
    }
    if (DB) __syncthreads();
#undef STAGE

    // C/D layout: col = lane&15, row = (lane>>4)*4 + reg   [m89-verified]
    const int cn = lane & 15, cr = (lane >> 4) * 4;

    if (mode == 0) {
        // LDS-repacked epilogue, 4 passes x 32 rows.
        const int which = (n0 >= 1536) ? 2 : (n0 >= 768 ? 1 : 0);
        const int nb = n0 - which * 768;
        u16* outP = (which == 0) ? outH : (which == 1) ? outH2 : outH3;
        u16* Cs = As;
        #pragma unroll
        for (int i = 0; i < 4; i++) {
            if (i) __syncthreads();
            #pragma unroll
            for (int j = 0; j < 4; j++) {
                const int n = n0 + wn + j * 16 + cn;
                const float bias = biasF[n];
                #pragma unroll
                for (int r = 0; r < 4; r++) {
                    Cs[((wave & 1) * 16 + cr + r) * 128 + wn + j * 16 + cn] =
                        f2us(acc[i][j][r] + bias);
                }
            }
            __syncthreads();
            if (which < 2) {
                // Q/K: row stores, 16 u16 per thread within one head's 64-run
                const int lr2 = tid >> 3, c2 = (tid & 7) * 16;
                const int m2 = m0 + (lr2 >> 4) * 64 + i * 16 + (lr2 & 15);
                const int bb2 = m2 >> 10, t2 = m2 & 1023;
                const int hh = (nb + c2) >> 6, d0 = (nb + c2) & 63;
                u16* dst = outP + (((size_t)(bb2 * HH + hh) * TT + t2) << 6) + d0;
                *reinterpret_cast<uint4*>(dst) =
                    *reinterpret_cast<const uint4*>(&Cs[lr2 * 128 + c2]);
                *reinterpret_cast<uint4*>(dst + 8) =
                    *reinterpret_cast<const uint4*>(&Cs[lr2 * 128 + c2 + 8]);
            } else {
                // V: transpose through LDS; 16B stores along t.
                const int nl = tid >> 1, half = tid & 1;
                const int hh = (nb + nl) >> 6, d = (nb + nl) & 63;
                #pragma unroll
                for (int seg = 0; seg < 2; seg++) {
                    u16 o[8];
                    #pragma unroll
                    for (int k = 0; k < 8; k++)
                        o[k] = Cs[(seg * 16 + half * 8 + k) * 128 + nl];
                    const int t0 = m0 + seg * 64 + i * 16 + half * 8;
                    const int bb2 = t0 >> 10, tt2 = t0 & 1023;
                    u16* dst = outP + (((size_t)(bb2 * HH + hh) * HD + d) << 10) + tt2;
                    *reinterpret_cast<uint4*>(dst) = *reinterpret_cast<uint4*>(o);
                }
            }
        }
        return;
    }

    if (mode == 2) {
        // LDS-repacked epilogue: 4 passes x 32 rows, dwordx4 coalesced stores
        u16* Cs = As;
        #pragma unroll
        for (int i = 0; i < 4; i++) {
            if (i) __syncthreads();
            int tokr[4]; float combr[4];
            #pragma unroll
            for (int r = 0; r < 4; r++)
                tokr[r] = rowtok[baseE + m0 + wm + i * 16 + cr + r];
            #pragma unroll
            for (int r = 0; r < 4; r++)
                combr[r] = comb[(size_t)tokr[r] * NE + z];
            #pragma unroll
            for (int j = 0; j < 4; j++) {
                const int n = n0 + wn + j * 16 + cn;
                const float bias = biasF[(size_t)z * biasZ + n];
                #pragma unroll
                for (int r = 0; r < 4; r++) {
                    float y = fmaxf(acc[i][j][r] + bias, 0.f) * combr[r];
                    Cs[((wave & 1) * 16 + cr + r) * 128 + wn + j * 16 + cn] = f2us(y);
                }
            }
            __syncthreads();
            const int lr2 = tid >> 3, c2 = (tid & 7) * 16;
            const int m2 = m0 + (lr2 >> 4) * 64 + i * 16 + (lr2 & 15);
            u16* dst = outH + (size_t)(baseE + m2) * ldc + n0 + c2;
            *reinterpret_cast<uint4*>(dst) =
                *reinterpret_cast<const uint4*>(&Cs[lr2 * 128 + c2]);
            *reinterpret_cast<uint4*>(dst + 8) =
                *reinterpret_cast<const uint4*>(&Cs[lr2 * 128 + c2 + 8]);
        }
        return;
    }

    #pragma unroll
    for (int i = 0; i < 4; i++) {
        #pragma unroll
        for (int j = 0; j < 4; j++) {
            const int n = n0 + wn + j * 16 + cn;
            #pragma unroll
            for (int r = 0; r < 4; r++) {
                const int m = m0 + wm + i * 16 + cr + r;
                // mode 3 (baseE=0) and mode 4 (compact rows)
                float* basep = outF + (size_t)z * cZ;
                basep[(size_t)(baseE + m) * ldc + n] = acc[i][j][r];
            }
        }
    }
}

// ---------------------------------------------------------------------------
// MFMA attention. Block = (qt 16 rows, head). 4 waves, QBLK=16.
// XCD-affine map (each XCD owns 3 heads; K/V L2-resident, FETCH 4.7 MB).
// CLOSED at ~54 us: dependency-chain / VALU-stall-bound (R6-R10 evidence:
// load-side fixes — occupancy, prefetch, L2 locality — all null on time).
// ---------------------------------------------------------------------------
#define PSTR 1032  // u16 stride: byte stride 2064 (16B aligned), dw 516 ≡ 4 mod 8 -> conflict-free b128
__global__ __launch_bounds__(256, 3) void attn_mfma_kernel(
    const u16* __restrict__ Qh, const u16* __restrict__ Kh,
    const u16* __restrict__ VT, const float* __restrict__ gamma_p,
    u16* __restrict__ attn_out)
{
    __shared__ __align__(16) u16 P[16 * PSTR];
    __shared__ __align__(16) float wred[4][16][4];
    __shared__ __align__(16) float dred[16][4];

    const int fid = blockIdx.x;
    const int xcd = fid & 7, rr = fid >> 3;
    const int bh = xcd * 3 + (rr >> 6);     // 24 heads: 3 per XCD
    const int qt = rr & 63;
    const int b = bh / HH, h = bh - b * HH;
    const int tid = threadIdx.x, wave = tid >> 6, lane = tid & 63;
    const int g = lane >> 4, fm = lane & 15;
    const float gamma = gamma_p[0];
    const int m0 = qt * 16;
    const u16* Qp = Qh + (size_t)bh * TT * HD;
    const u16* Kp = Kh + (size_t)bh * TT * HD;
    const u16* Vp = VT + (size_t)bh * HD * TT;

    bf16x8 af[2];
    #pragma unroll
    for (int ks = 0; ks < 2; ks++)
        af[ks] = *reinterpret_cast<const bf16x8*>(
            Qp + (size_t)(m0 + fm) * HD + ks * 32 + g * 8);

    const int n0w = wave * 256;
    f32x4 acc[16] = {};
    #pragma unroll
    for (int nj = 0; nj < 16; nj++) {
        const u16* kp = Kp + (size_t)(n0w + nj * 16 + fm) * HD + g * 8;
        bf16x8 b0 = *reinterpret_cast<const bf16x8*>(kp);
        bf16x8 b1 = *reinterpret_cast<const bf16x8*>(kp + 32);
        acc[nj] = MFMA16(af[0], b0, acc[nj]);
        acc[nj] = MFMA16(af[1], b1, acc[nj]);
    }

    // ---- per-wave row stats -> LDS ----
    #pragma unroll
    for (int r = 0; r < 4; r++) {
        float s1 = 0.f, s2 = 0.f, mx = -3.4e38f, mn = 3.4e38f;
        #pragma unroll
        for (int nj = 0; nj < 16; nj++) {
            float v = acc[nj][r];
            s1 += v; s2 = fmaf(v, v, s2);
            mx = fmaxf(mx, v); mn = fminf(mn, v);
        }
        #pragma unroll
        for (int msk = 1; msk < 16; msk <<= 1) {
            s1 += __shfl_xor(s1, msk);
            s2 += __shfl_xor(s2, msk);
            mx = fmaxf(mx, __shfl_xor(mx, msk));
            mn = fminf(mn, __shfl_xor(mn, msk));
        }
        if (fm == 0) {
            const int row = g * 4 + r;
            wred[wave][row][0] = s1; wred[wave][row][1] = s2;
            wred[wave][row][2] = mx; wred[wave][row][3] = mn;
        }
    }
    __syncthreads();   // barrier 1: wred complete

    // ---- inline combine + softmax (a/cm are loop-local temps) ----
    #pragma unroll
    for (int r = 0; r < 4; r++) {
        const int row = g * 4 + r;
        float s1 = 0.f, s2 = 0.f, mx = -3.4e38f, mn = 3.4e38f;
        #pragma unroll
        for (int w = 0; w < 4; w++) {
            float4 t = *reinterpret_cast<const float4*>(&wred[w][row][0]);
            s1 += t.x; s2 += t.y;
            mx = fmaxf(mx, t.z); mn = fminf(mn, t.w);
        }
        float var = (s2 - s1 * s1 * (1.f / TT)) * (1.f / (TT - 1));
        var = fmaxf(var, 0.f);
        const float a = gamma / (sqrtf(var) + 8e-5f);
        const float cm = (a >= 0.f) ? a * mx : a * mn;
        float dp = 0.f;
        #pragma unroll
        for (int nj = 0; nj < 16; nj++) {
            float p = __expf(fmaf(a, acc[nj][r], -cm));
            u16 pb = f2us(p);
            dp += us2f(pb);
            P[row * PSTR + n0w + nj * 16 + fm] = pb;
        }
        #pragma unroll
        for (int msk = 1; msk < 16; msk <<= 1) dp += __shfl_xor(dp, msk);
        if (fm == 0) dred[row][wave] = dp;
    }
    __syncthreads();   // barrier 2: P + dred complete

    // ---- PV (direct loads) ----
    f32x4 oacc = {};
    #pragma unroll 8
    for (int ks = 0; ks < 32; ks++) {
        bf16x8 bv = *reinterpret_cast<const bf16x8*>(
            Vp + (size_t)(wave * 16 + fm) * TT + ks * 32 + g * 8);
        bf16x8 a0 = *reinterpret_cast<const bf16x8*>(&P[(size_t)fm * PSTR + ks * 32 + g * 8]);
        oacc = MFMA16(a0, bv, oacc);
    }

    // ---- epilogue: dinv folded here ----
    #pragma unroll
    for (int r = 0; r < 4; r++) {
        const int row = g * 4 + r;
        float4 dv = *reinterpret_cast<const float4*>(&dred[row][0]);
        const float dinv = 1.f / (dv.x + dv.y + dv.z + dv.w);
        const int t = m0 + row;
        attn_out[((size_t)(b * TT + t)) * DD + h * HD + wave * 16 + fm] =
            f2us(oacc[r] * dinv);
    }
}

// ---------------------------------------------------------------------------
// LN1 fused + gate (2 Wo partials now): r1 = p0+p1 + src + bo; layernorm ->
// x fp32 + xh bf16; gate on in-register post-LN values; thread-0 top-2.
// ---------------------------------------------------------------------------
__global__ __launch_bounds__(256) void ln1_kernel(
    const float* __restrict__ p0, const float* __restrict__ p1,
    const float* __restrict__ src, const float* __restrict__ bo,
    const float* __restrict__ g, const float* __restrict__ bta,
    const float* __restrict__ Wg, const float* __restrict__ bg,
    float* __restrict__ outF, u16* __restrict__ outH,
    float* __restrict__ comb, int* __restrict__ epack)
{
    const int row = blockIdx.x, tid = threadIdx.x;
    __shared__ float red[256];
    __shared__ float gred[4][4];
    const size_t base = (size_t)row * DD;
    float v[3];
    #pragma unroll
    for (int i = 0; i < 3; i++) {
        int c = tid + i * 256;
        v[i] = p0[base + c] + p1[base + c] + src[base + c] + bo[c];
    }
    float s = v[0] + v[1] + v[2];
    red[tid] = s; __syncthreads();
    #pragma unroll
    for (int o = 128; o > 0; o >>= 1) { if (tid < o) red[tid] += red[tid + o]; __syncthreads(); }
    const float mean = red[0] * (1.f / 768.f);
    __syncthreads();
    float qv = 0.f;
    #pragma unroll
    for (int i = 0; i < 3; i++) { float d = v[i] - mean; qv += d * d; }
    red[tid] = qv; __syncthreads();
    #pragma unroll
    for (int o = 128; o > 0; o >>= 1) { if (tid < o) red[tid] += red[tid + o]; __syncthreads(); }
    const float var = red[0] * (1.f / 768.f);
    const float rs = rsqrtf(var + 1e-5f);
    float ga0 = 0.f, ga1 = 0.f, ga2 = 0.f, ga3 = 0.f;
    #pragma unroll
    for (int i = 0; i < 3; i++) {
        int c = tid + i * 256;
        float o = (v[i] - mean) * rs * g[c] + bta[c];
        outF[base + c] = o;
        outH[base + c] = f2us(o);
        ga0 = fmaf(o, Wg[c], ga0);
        ga1 = fmaf(o, Wg[DD + c], ga1);
        ga2 = fmaf(o, Wg[2 * DD + c], ga2);
        ga3 = fmaf(o, Wg[3 * DD + c], ga3);
    }
    #pragma unroll
    for (int off = 32; off > 0; off >>= 1) {
        ga0 += __shfl_down(ga0, off, 64);
        ga1 += __shfl_down(ga1, off, 64);
        ga2 += __shfl_down(ga2, off, 64);
        ga3 += __shfl_down(ga3, off, 64);
    }
    const int wave = tid >> 6, lane = tid & 63;
    if (lane == 0) {
        gred[wave][0] = ga0; gred[wave][1] = ga1;
        gred[wave][2] = ga2; gred[wave][3] = ga3;
    }
    __syncthreads();
    if (tid == 0) {
        float gg[NE];
        #pragma unroll
        for (int e = 0; e < NE; e++)
            gg[e] = gred[0][e] + gred[1][e] + gred[2][e] + gred[3][e] + bg[e];
        float m = -1e30f;
        #pragma unroll
        for (int e = 0; e < NE; e++) m = fmaxf(m, gg[e]);
        float ex[NE], ssum = 0.f;
        #pragma unroll
        for (int e = 0; e < NE; e++) { ex[e] = __expf(gg[e] - m); ssum += ex[e]; }
        #pragma unroll
        for (int e = 0; e < NE; e++) ex[e] /= ssum;
        int e1 = 0;
        #pragma unroll
        for (int e = 1; e < NE; e++) if (ex[e] > ex[e1]) e1 = e;
        int e2 = -1;
        #pragma unroll
        for (int e = 0; e < NE; e++) if (e != e1 && (e2 < 0 || ex[e] > ex[e2])) e2 = e;
        float c[NE] = {0.f, 0.f, 0.f, 0.f};
        c[e1] = ex[e1]; c[e2] = ex[e2];
        #pragma unroll
        for (int e = 0; e < NE; e++) comb[(size_t)row * NE + e] = c[e];
        epack[row] = e1 | (e2 << 4);
    }
}

// ---------------------------------------------------------------------------
// LN2 (compact, 2 slabs): t = x + sum_{z<2} sum_{i<2} pslab[z][tok2row[t,i]]
// + comb*b2; layernorm -> out.
// ---------------------------------------------------------------------------
__global__ __launch_bounds__(256) void ln2_kernel(
    const float* __restrict__ x, const float* __restrict__ pslab,
    const int* __restrict__ tok2row,
    const float* __restrict__ comb, const float* __restrict__ b2,
    const float* __restrict__ g, const float* __restrict__ bta,
    float* __restrict__ outF)
{
    const int row = blockIdx.x, tid = threadIdx.x;
    __shared__ float red[256];
    const size_t base = (size_t)row * DD;
    const int r0 = tok2row[row * 2], r1 = tok2row[row * 2 + 1];
    const float* q0 = pslab + (size_t)r0 * DD;
    const float* q1 = pslab + (size_t)r1 * DD;
    const float c0 = comb[row * NE + 0], c1 = comb[row * NE + 1];
    const float c2 = comb[row * NE + 2], c3 = comb[row * NE + 3];
    float v[3];
    #pragma unroll
    for (int i = 0; i < 3; i++) {
        int c = tid + i * 256;
        float t = x[base + c];
        t += q0[c] + q0[SLABZ + c];
        t += q1[c] + q1[SLABZ + c];
        t = fmaf(c0, b2[c], t);
        t = fmaf(c1, b2[DD + c], t);
        t = fmaf(c2, b2[2 * DD + c], t);
        t = fmaf(c3, b2[3 * DD + c], t);
        v[i] = t;
    }
    float s = v[0] + v[1] + v[2];
    red[tid] = s; __syncthreads();
    #pragma unroll
    for (int o = 128; o > 0; o >>= 1) { if (tid < o) red[tid] += red[tid + o]; __syncthreads(); }
    const float mean = red[0] * (1.f / 768.f);
    __syncthreads();
    float qv = 0.f;
    #pragma unroll
    for (int i = 0; i < 3; i++) { float d = v[i] - mean; qv += d * d; }
    red[tid] = qv; __syncthreads();
    #pragma unroll
    for (int o = 128; o > 0; o >>= 1) { if (tid < o) red[tid] += red[tid + o]; __syncthreads(); }
    const float var = red[0] * (1.f / 768.f);
    const float rs = rsqrtf(var + 1e-5f);
    #pragma unroll
    for (int i = 0; i < 3; i++) {
        int c = tid + i * 256;
        outF[base + c] = (v[i] - mean) * rs * g[c] + bta[c];
    }
}

extern "C" void kernel_launch(void* const* d_in, const int* in_sizes, int n_in,
                              void* d_out, int out_size, void* d_ws, size_t ws_size,
                              hipStream_t stream)
{
    const float* src  = (const float*)d_in[0];
    const float* Wq   = (const float*)d_in[2];  const float* bq = (const float*)d_in[3];
    const float* Wk   = (const float*)d_in[4];  const float* bk = (const float*)d_in[5];
    const float* Wv   = (const float*)d_in[6];  const float* bv = (const float*)d_in[7];
    const float* Wo   = (const float*)d_in[8];  const float* bo = (const float*)d_in[9];
    const float* gam  = (const float*)d_in[10];
    const float* ln1g = (const float*)d_in[11]; const float* ln1b = (const float*)d_in[12];
    const float* ln2g = (const float*)d_in[13]; const float* ln2b = (const float*)d_in[14];
    const float* Wg   = (const float*)d_in[15]; const float* bg = (const float*)d_in[16];
    const float* W1   = (const float*)d_in[17]; const float* b1 = (const float*)d_in[18];
    const float* W2   = (const float*)d_in[19]; const float* b2 = (const float*)d_in[20];
    (void)ws_size; (void)in_sizes; (void)n_in; (void)out_size;

    char* ws = (char*)d_ws;
    u16*   W1T  = (u16*)(ws);
    float* wop  = (float*)(ws + 18874368);             // 2 slabs x 6.29 MB (Wo partials)
    float* pslab= (float*)(ws);                        // 2 slabs x 14.2 MB (after FF1)
    u16*   W2T  = (u16*)(ws + 56623104);               // 18,874,368 (live through FF2)
    u16*   hb   = (u16*)(ws + 75497472);               // 28,311,552 compact FF1 out [CROWS][3072]
    float* x    = (float*)(ws + 103809024);            //  6,291,456
    u16*   xh   = (u16*)(ws + 110100480);              //  3,145,728
    float* comb = (float*)(ws + 113246208);            //     32,768
    float* bqkv = (float*)(ws + 113278976);            //      9,216
    int*   cnt    = (int*)(ws + 113288192);            //         64
    int*   rowtok = (int*)(ws + 113288256);            //     18,432 (CROWS)
    int*   epack  = (int*)(ws + 113306688);            //      8,192
    int*   tok2row= (int*)(ws + 113323072);            //     16,384
    // attn-phase aliases inside hb region (all dead before FF1 writes hb)
    char* H = ws + 75497472;
    u16*   Qh     = (u16*)(H);
    u16*   Kh     = (u16*)(H + 3145728);
    u16*   VTh    = (u16*)(H + 6291456);
    u16*   src_h  = (u16*)(H + 9437184);
    u16*   attn_h = (u16*)(H + 12582912);
    u16*   WqkvH  = (u16*)(H + 15728640);
    u16*   WoH    = (u16*)(H + 19267584);
    const long PZ = (long)NTOK * DD;

    // ---- single fused conversion launch (src + weights + biases + W1T/W2T) ----
    convert_all_kernel<<<20353, 256, 0, stream>>>(
        src, Wq, Wk, Wv, Wo, bq, bk, bv, W1, W2,
        src_h, WqkvH, WoH, bqkv, W1T, W2T);

    // ---- QKV (dbuf prefetch, XCD-chunked flat 288) ----
    gemm_bt_kernel<1><<<dim3(288, 1, 1), 256, 0, stream>>>(
        src_h, DD, 0, WqkvH, DD, 0, DD, 0, 2,
        nullptr, Qh, Kh, VTh, 0, 0, bqkv, 0, nullptr, nullptr, nullptr);

    // ---- attention (MFMA, XCD-affine head map) ----
    attn_mfma_kernel<<<dim3(1536, 1, 1), 256, 0, stream>>>(
        Qh, Kh, VTh, gam, attn_h);

    // ---- Wo projection split-K x2 (K=384/slice, 6 BK-iters; partial
    //      traffic halved vs x4) -> fp32 partials ----
    gemm_bt_kernel<1><<<dim3(DD / 128, NTOK / 128, 2), 256, 0, stream>>>(
        attn_h, DD, 384L, WoH, DD, 384L, 384, 3, 0,
        wop, nullptr, nullptr, nullptr, DD, PZ, nullptr, 0, nullptr, nullptr, nullptr);

    // ---- LN1 + fused gate (2 partials) ----
    ln1_kernel<<<NTOK, 256, 0, stream>>>(
        wop, wop + PZ, src, bo,
        ln1g, ln1b, Wg, bg, x, xh, comb, epack);

    // ---- deterministic slot assignment (single-block prefix scan) ----
    scan_build_kernel<<<1, 256, 0, stream>>>(epack, cnt, rowtok, tok2row);

    // ---- FF1 compact (top-2 only), single-buffer (occupancy) ----
    gemm_bt_kernel<0><<<dim3(1536, 1, 1), 256, 0, stream>>>(
        xh, DD, 0, W1T, DD, (long)FFD * DD, DD, 2, 1,
        nullptr, hb, nullptr, nullptr, FFD, 0, b1, FFD, rowtok, cnt, comb);

    // ---- FF2 compact: per-expert K=3072 split-K x2, flat 768 ----
    gemm_bt_kernel<0><<<dim3(768, 1, 1), 256, 0, stream>>>(
        hb, FFD, 1536L, W2T, FFD, 1536L, 1536, 4, 3,
        pslab, nullptr, nullptr, nullptr, DD, SLABZ, nullptr, 0, rowtok, cnt, nullptr);

    // ---- LN2 (x + gathered 2-slab partials + comb*b2, then layernorm) ----
    ln2_kernel<<<NTOK, 256, 0, stream>>>(
        x, pslab, tok2row, comb, b2, ln2g, ln2b, (float*)d_out);
}